// Round 4
// baseline (1206.368 us; speedup 1.0000x reference)
//
#include <hip/hip_runtime.h>
#include <hip/hip_bf16.h>

// ---------------- problem constants ----------------
constexpr int Bn   = 8;
constexpr int L    = 4096;
constexpr int E    = 256;
constexpr int Lh   = 2048;   // after maxpool(2)
constexpr int C1n  = 128;
constexpr int Dlat = 256;
constexpr int Din  = 512;
constexpr int Nst  = 16;
constexpr int Dtr  = 16;
constexpr int M2   = Bn * Lh;   // 16384 rows for all mamba GEMMs

// ---------------- workspace layout (float offsets) ----------------
constexpr long o_wt1   = 0;                       // [5][256][128]
constexpr long o_wt2   = o_wt1  + 5L*256*128;     // [3][128][256]
constexpr long o_wtin  = o_wt2  + 3L*128*256;     // [256][1024]
constexpr long o_wtx   = o_wtin + 256L*1024;      // [512][48]
constexpr long o_wtdt  = o_wtx  + 512L*48;        // [16][512]
constexpr long o_wtout = o_wtdt + 16L*512;        // [512][256]
constexpr long o_endw  = o_wtout + 512L*256;      // = 688128
constexpr long o_bufA  = o_endw;                  // xe [8][4096][256] -> later x [8][2048][512]
constexpr long o_bufB  = o_bufA + (long)Bn*L*E;       // out1 [8][2048][128] -> later dbc [16384][48]
constexpr long o_bufC  = o_bufB + (long)Bn*Lh*C1n;    // u [16384][256] -> later yo [16384][256]
constexpr long o_bufD  = o_bufC + (long)M2*Dlat;      // xz [16384][1024]
constexpr long o_bufG  = o_bufD + (long)M2*2*Din;     // dt [16384][512]
constexpr long o_bufH  = o_bufG + (long)M2*Din;       // y_final [16384][512]
constexpr long o_bufX  = o_bufH + (long)M2*Din;       // mean sums [8][256]

// ---------------- weight pre-transpose ----------------
__global__ void k_prep(const float* __restrict__ w1, const float* __restrict__ w2,
                       const float* __restrict__ win, const float* __restrict__ xw,
                       const float* __restrict__ dtw, const float* __restrict__ ow,
                       float* __restrict__ ws) {
    int idx = blockIdx.x * 256 + threadIdx.x;
    if (idx < 163840) {                       // wt1[k][c][o] = w1[o][c][k]
        int o = idx & 127; int rem = idx >> 7; int c = rem & 255; int k = rem >> 8;
        ws[o_wt1 + idx] = w1[(o*256 + c)*5 + k];
    } else if (idx < 262144) {                // wt2[k][c][o] = w2[o][c][k]
        int j = idx - 163840;
        int o = j & 255; int rem = j >> 8; int c = rem & 127; int k = rem >> 7;
        ws[o_wt2 + j] = w2[(o*128 + c)*3 + k];
    } else if (idx < 524288) {                // wtin[k][n] = win[n][k]
        int j = idx - 262144;
        int n_ = j & 1023; int k = j >> 10;
        ws[o_wtin + j] = win[n_*256 + k];
    } else if (idx < 548864) {                // wtx[k][n] = xw[n][k]
        int j = idx - 524288;
        int n_ = j % 48; int k = j / 48;
        ws[o_wtx + j] = xw[n_*512 + k];
    } else if (idx < 557056) {                // wtdt[k][n] = dtw[n][k]
        int j = idx - 548864;
        int n_ = j & 511; int k = j >> 9;
        ws[o_wtdt + j] = dtw[n_*16 + k];
    } else if (idx < 688128) {                // wtout[k][n] = ow[n][k]
        int j = idx - 557056;
        int n_ = j & 255; int k = j >> 8;
        ws[o_wtout + j] = ow[n_*512 + k];
    }
}

// ---------------- embedding gather ----------------
__global__ void k_embed(const int* __restrict__ tok, const float* __restrict__ emb,
                        float* __restrict__ xe) {
    int idx = blockIdx.x * 256 + threadIdx.x;     // float4 index
    int row = idx >> 6;                           // 64 float4 per row (E=256)
    int c4  = idx & 63;
    int t = tok[row];
    ((float4*)xe)[(long)row*64 + c4] = ((const float4*)emb)[(long)t*64 + c4];
}

// ---------------- conv1 (K=1280) + ReLU + maxpool(2) ----------------
// out1[b][tp][o] over [8][2048][128]
__global__ __launch_bounds__(256) void k_conv1_pool(const float* __restrict__ xe,
                                                    const float* __restrict__ wt1,
                                                    const float* __restrict__ b1,
                                                    float* __restrict__ out1) {
    __shared__ float As[32][33];
    __shared__ float Bs[32][128];
    int t0  = blockIdx.x * 32;
    int b   = blockIdx.y;
    int tid = threadIdx.x;
    int ti  = tid >> 5;    // 0..7 : 4 conv-time rows each
    int oj  = tid & 31;    // 0..31: 4 output channels each
    float acc[4][4] = {};
    for (int k = 0; k < 5; ++k) {
        for (int c0 = 0; c0 < 256; c0 += 32) {
            { // A tile: 32 time rows x 32 channels
                int tt = tid >> 3, q = tid & 7;
                int tg = t0 + tt + k - 2;
                float4 v = {0.f,0.f,0.f,0.f};
                if (tg >= 0 && tg < L)
                    v = *(const float4*)&xe[((long)b*L + tg)*E + c0 + q*4];
                As[tt][q*4+0] = v.x; As[tt][q*4+1] = v.y;
                As[tt][q*4+2] = v.z; As[tt][q*4+3] = v.w;
            }
            #pragma unroll
            for (int r = 0; r < 4; ++r) { // B tile: 32 c x 128 o
                int idx = tid + r*256;
                int cc = idx >> 5, o4 = idx & 31;
                *(float4*)&Bs[cc][o4*4] =
                    *(const float4*)&wt1[((long)(k*256 + c0 + cc))*128 + o4*4];
            }
            __syncthreads();
            #pragma unroll
            for (int kk = 0; kk < 32; ++kk) {
                float4 bv = *(float4*)&Bs[kk][oj*4];
                float a0 = As[ti*4+0][kk], a1 = As[ti*4+1][kk];
                float a2 = As[ti*4+2][kk], a3 = As[ti*4+3][kk];
                acc[0][0] += a0*bv.x; acc[0][1] += a0*bv.y; acc[0][2] += a0*bv.z; acc[0][3] += a0*bv.w;
                acc[1][0] += a1*bv.x; acc[1][1] += a1*bv.y; acc[1][2] += a1*bv.z; acc[1][3] += a1*bv.w;
                acc[2][0] += a2*bv.x; acc[2][1] += a2*bv.y; acc[2][2] += a2*bv.z; acc[2][3] += a2*bv.w;
                acc[3][0] += a3*bv.x; acc[3][1] += a3*bv.y; acc[3][2] += a3*bv.z; acc[3][3] += a3*bv.w;
            }
            __syncthreads();
        }
    }
    float4 bias = *(const float4*)&b1[oj*4];
    float r[4][4];
    #pragma unroll
    for (int i = 0; i < 4; ++i) {
        r[i][0] = fmaxf(acc[i][0] + bias.x, 0.f);
        r[i][1] = fmaxf(acc[i][1] + bias.y, 0.f);
        r[i][2] = fmaxf(acc[i][2] + bias.z, 0.f);
        r[i][3] = fmaxf(acc[i][3] + bias.w, 0.f);
    }
    float4 v0, v1;
    v0.x = fmaxf(r[0][0], r[1][0]); v0.y = fmaxf(r[0][1], r[1][1]);
    v0.z = fmaxf(r[0][2], r[1][2]); v0.w = fmaxf(r[0][3], r[1][3]);
    v1.x = fmaxf(r[2][0], r[3][0]); v1.y = fmaxf(r[2][1], r[3][1]);
    v1.z = fmaxf(r[2][2], r[3][2]); v1.w = fmaxf(r[2][3], r[3][3]);
    int tp0 = (t0 + ti*4) >> 1;
    *(float4*)&out1[((long)b*Lh + tp0    )*C1n + oj*4] = v0;
    *(float4*)&out1[((long)b*Lh + tp0 + 1)*C1n + oj*4] = v1;
}

// ---------------- conv2 (K=384) + ReLU ----------------
// u[b][t][o] over [8][2048][256]
__global__ __launch_bounds__(256) void k_conv2(const float* __restrict__ in,
                                               const float* __restrict__ wt2,
                                               const float* __restrict__ b2,
                                               float* __restrict__ out) {
    __shared__ float As[32][33];
    __shared__ float Bs[32][128];
    int t0 = blockIdx.x * 32;
    int o0 = blockIdx.y * 128;
    int b  = blockIdx.z;
    int tid = threadIdx.x;
    int ti  = tid >> 5;
    int oj  = tid & 31;
    float acc[4][4] = {};
    for (int k = 0; k < 3; ++k) {
        for (int c0 = 0; c0 < 128; c0 += 32) {
            {
                int tt = tid >> 3, q = tid & 7;
                int tg = t0 + tt + k - 1;
                float4 v = {0.f,0.f,0.f,0.f};
                if (tg >= 0 && tg < Lh)
                    v = *(const float4*)&in[((long)b*Lh + tg)*C1n + c0 + q*4];
                As[tt][q*4+0] = v.x; As[tt][q*4+1] = v.y;
                As[tt][q*4+2] = v.z; As[tt][q*4+3] = v.w;
            }
            #pragma unroll
            for (int r = 0; r < 4; ++r) {
                int idx = tid + r*256;
                int cc = idx >> 5, o4 = idx & 31;
                *(float4*)&Bs[cc][o4*4] =
                    *(const float4*)&wt2[((long)(k*128 + c0 + cc))*256 + o0 + o4*4];
            }
            __syncthreads();
            #pragma unroll
            for (int kk = 0; kk < 32; ++kk) {
                float4 bv = *(float4*)&Bs[kk][oj*4];
                float a0 = As[ti*4+0][kk], a1 = As[ti*4+1][kk];
                float a2 = As[ti*4+2][kk], a3 = As[ti*4+3][kk];
                acc[0][0] += a0*bv.x; acc[0][1] += a0*bv.y; acc[0][2] += a0*bv.z; acc[0][3] += a0*bv.w;
                acc[1][0] += a1*bv.x; acc[1][1] += a1*bv.y; acc[1][2] += a1*bv.z; acc[1][3] += a1*bv.w;
                acc[2][0] += a2*bv.x; acc[2][1] += a2*bv.y; acc[2][2] += a2*bv.z; acc[2][3] += a2*bv.w;
                acc[3][0] += a3*bv.x; acc[3][1] += a3*bv.y; acc[3][2] += a3*bv.z; acc[3][3] += a3*bv.w;
            }
            __syncthreads();
        }
    }
    float4 bias = *(const float4*)&b2[o0 + oj*4];
    #pragma unroll
    for (int i = 0; i < 4; ++i) {
        int t = t0 + ti*4 + i;
        float4 v;
        v.x = fmaxf(acc[i][0] + bias.x, 0.f);
        v.y = fmaxf(acc[i][1] + bias.y, 0.f);
        v.z = fmaxf(acc[i][2] + bias.z, 0.f);
        v.w = fmaxf(acc[i][3] + bias.w, 0.f);
        *(float4*)&out[((long)b*Lh + t)*Dlat + o0 + oj*4] = v;
    }
}

// ---------------- generic fp32 GEMM: out[M][N] = act(A[M][K(lda)] @ WT[K][N] + bias) ----------------
template<int ACT>   // 0 = none, 1 = softplus
__global__ __launch_bounds__(256) void k_gemm(const float* __restrict__ A, int lda,
                                              const float* __restrict__ WT,
                                              const float* __restrict__ bias,
                                              float* __restrict__ out,
                                              int M, int N, int K) {
    __shared__ float As[16][68];
    __shared__ float Bs[16][64];
    int n0 = blockIdx.x * 64, m0 = blockIdx.y * 64;
    int tid = threadIdx.x;
    int ti = tid >> 4, tj = tid & 15;
    float acc[4][4] = {};
    for (int k0 = 0; k0 < K; k0 += 16) {
        {
            int mm = tid >> 2, kq = tid & 3;
            float4 v = *(const float4*)&A[(long)(m0 + mm)*lda + k0 + kq*4];
            As[kq*4+0][mm] = v.x; As[kq*4+1][mm] = v.y;
            As[kq*4+2][mm] = v.z; As[kq*4+3][mm] = v.w;
        }
        {
            int kk = tid >> 4, n4 = tid & 15;
            float4 v = {0.f,0.f,0.f,0.f};
            if (n0 + n4*4 < N)
                v = *(const float4*)&WT[(long)(k0 + kk)*N + n0 + n4*4];
            *(float4*)&Bs[kk][n4*4] = v;
        }
        __syncthreads();
        #pragma unroll
        for (int kk = 0; kk < 16; ++kk) {
            float4 av = *(float4*)&As[kk][ti*4];
            float4 bv = *(float4*)&Bs[kk][tj*4];
            acc[0][0] += av.x*bv.x; acc[0][1] += av.x*bv.y; acc[0][2] += av.x*bv.z; acc[0][3] += av.x*bv.w;
            acc[1][0] += av.y*bv.x; acc[1][1] += av.y*bv.y; acc[1][2] += av.y*bv.z; acc[1][3] += av.y*bv.w;
            acc[2][0] += av.z*bv.x; acc[2][1] += av.z*bv.y; acc[2][2] += av.z*bv.z; acc[2][3] += av.z*bv.w;
            acc[3][0] += av.w*bv.x; acc[3][1] += av.w*bv.y; acc[3][2] += av.w*bv.z; acc[3][3] += av.w*bv.w;
        }
        __syncthreads();
    }
    if (n0 + tj*4 >= N) return;
    float4 bv = {0.f,0.f,0.f,0.f};
    if (bias) bv = *(const float4*)&bias[n0 + tj*4];
    #pragma unroll
    for (int i = 0; i < 4; ++i) {
        int m = m0 + ti*4 + i;
        float4 v;
        v.x = acc[i][0] + bv.x; v.y = acc[i][1] + bv.y;
        v.z = acc[i][2] + bv.z; v.w = acc[i][3] + bv.w;
        if (ACT == 1) {  // softplus
            v.x = (v.x > 20.f) ? v.x : log1pf(__expf(v.x));
            v.y = (v.y > 20.f) ? v.y : log1pf(__expf(v.y));
            v.z = (v.z > 20.f) ? v.z : log1pf(__expf(v.z));
            v.w = (v.w > 20.f) ? v.w : log1pf(__expf(v.w));
        }
        *(float4*)&out[(long)m*N + n0 + tj*4] = v;
    }
}

// ---------------- causal depthwise conv (k=4) + SiLU ----------------
__global__ void k_dwconv(const float* __restrict__ xz, const float* __restrict__ wdw,
                         const float* __restrict__ bdw, float* __restrict__ xout) {
    int idx = blockIdx.x * 256 + threadIdx.x;       // (b,t,d4)
    int d4 = idx & 127; int rem = idx >> 7;
    int t = rem & 2047; int b = rem >> 11;
    int d0 = d4 * 4;
    float4 acc = *(const float4*)&bdw[d0];
    #pragma unroll
    for (int k = 0; k < 4; ++k) {
        int tt = t - 3 + k;
        if (tt >= 0) {
            float4 v = *(const float4*)&xz[((long)(b*Lh + tt))*1024 + d0];
            acc.x += v.x * wdw[(d0+0)*4 + k];
            acc.y += v.y * wdw[(d0+1)*4 + k];
            acc.z += v.z * wdw[(d0+2)*4 + k];
            acc.w += v.w * wdw[(d0+3)*4 + k];
        }
    }
    acc.x = acc.x / (1.f + __expf(-acc.x));
    acc.y = acc.y / (1.f + __expf(-acc.y));
    acc.z = acc.z / (1.f + __expf(-acc.z));
    acc.w = acc.w / (1.f + __expf(-acc.w));
    *(float4*)&xout[(long)idx * 4] = acc;
}

// ---------------- selective scan, fused with +x*Dp and *silu(z) ----------------
// 16 lanes per (b,d) channel (one per state); 16 channels per block.
__global__ __launch_bounds__(256) void k_scan(const float* __restrict__ dt,
                                              const float* __restrict__ x,
                                              const float* __restrict__ xz,
                                              const float* __restrict__ dbc,
                                              const float* __restrict__ A_log,
                                              const float* __restrict__ Dp,
                                              float* __restrict__ yf) {
    __shared__ float dt_s[64][16], x_s[64][16], z_s[64][16];
    __shared__ float Bs_[64][16], Cs_[64][16], ys[64][16];
    int blk = blockIdx.x;
    int b = blk >> 5; int d0 = (blk & 31) * 16;
    int tid = threadIdx.x;
    int lane = tid & 63; int wave = tid >> 6;
    int g = lane >> 4; int n = lane & 15;
    int ch = wave * 4 + g; int d = d0 + ch;
    float Areg = -__expf(A_log[d*16 + n]);
    float Dpv  = Dp[d];
    float h = 0.f;
    int row = tid >> 2, q = (tid & 3) * 4;
    for (int t0 = 0; t0 < Lh; t0 += 64) {
        long base = (long)b*Lh + t0 + row;
        *(float4*)&dt_s[row][q] = *(const float4*)&dt[base*512 + d0 + q];
        *(float4*)&x_s[row][q]  = *(const float4*)&x[base*512 + d0 + q];
        *(float4*)&z_s[row][q]  = *(const float4*)&xz[base*1024 + 512 + d0 + q];
        *(float4*)&Bs_[row][q]  = *(const float4*)&dbc[base*48 + 16 + q];
        *(float4*)&Cs_[row][q]  = *(const float4*)&dbc[base*48 + 32 + q];
        __syncthreads();
        for (int tt = 0; tt < 64; ++tt) {
            float dtv = dt_s[tt][ch];
            float xv  = x_s[tt][ch];
            float bvv = Bs_[tt][n];
            float cv  = Cs_[tt][n];
            float dA  = __expf(dtv * Areg);
            h = h * dA + dtv * xv * bvv;
            float p = h * cv;
            p += __shfl_xor(p, 1);
            p += __shfl_xor(p, 2);
            p += __shfl_xor(p, 4);
            p += __shfl_xor(p, 8);
            if (n == 0) {
                float zv = z_s[tt][ch];
                float sz = zv / (1.f + __expf(-zv));
                ys[tt][ch] = (p + xv * Dpv) * sz;
            }
        }
        __syncthreads();
        *(float4*)&yf[base*512 + d0 + q] = *(float4*)&ys[row][q];
    }
}

// ---------------- mean over t (partial sums + atomics) ----------------
__global__ void k_meanpart(const float* __restrict__ yo, float* __restrict__ xm) {
    int chunk = blockIdx.x & 31;
    int b = blockIdx.x >> 5;
    int c = threadIdx.x;
    float s = 0.f;
    int t0 = chunk * 64;
    #pragma unroll 4
    for (int t = t0; t < t0 + 64; ++t)
        s += yo[((long)b*Lh + t)*Dlat + c];
    atomicAdd(&xm[b*Dlat + c], s);
}

// ---------------- final fc ----------------
__global__ void k_fc(const float* __restrict__ xm, const float* __restrict__ fcw,
                     const float* __restrict__ fcb, float* __restrict__ out) {
    int tid = threadIdx.x;
    if (tid < 80) {
        int b = tid / 10, o = tid % 10;
        float s = 0.f;
        for (int c = 0; c < Dlat; ++c)
            s += xm[b*Dlat + c] * fcw[o*Dlat + c];
        out[tid] = s * (1.f / 2048.f) + fcb[o];
    }
}

extern "C" void kernel_launch(void* const* d_in, const int* in_sizes, int n_in,
                              void* d_out, int out_size, void* d_ws, size_t ws_size,
                              hipStream_t stream) {
    const int*   tok  = (const int*)d_in[0];
    const float* emb  = (const float*)d_in[1];
    const float* w1   = (const float*)d_in[2];
    const float* b1   = (const float*)d_in[3];
    const float* w2   = (const float*)d_in[4];
    const float* b2   = (const float*)d_in[5];
    const float* win  = (const float*)d_in[6];
    const float* wdw  = (const float*)d_in[7];
    const float* bdw  = (const float*)d_in[8];
    const float* xw   = (const float*)d_in[9];
    const float* dtw  = (const float*)d_in[10];
    const float* dtb  = (const float*)d_in[11];
    const float* alog = (const float*)d_in[12];
    const float* Dp   = (const float*)d_in[13];
    const float* ow   = (const float*)d_in[14];
    const float* fcw  = (const float*)d_in[15];
    const float* fcb  = (const float*)d_in[16];
    float* ws  = (float*)d_ws;
    float* out = (float*)d_out;

    float* wt1   = ws + o_wt1;
    float* wt2   = ws + o_wt2;
    float* wtin  = ws + o_wtin;
    float* wtx   = ws + o_wtx;
    float* wtdt  = ws + o_wtdt;
    float* wtout = ws + o_wtout;
    float* xe    = ws + o_bufA;   // later reused as x (post dwconv+silu)
    float* out1  = ws + o_bufB;   // later reused as dbc
    float* u     = ws + o_bufC;   // later reused as yo
    float* xz    = ws + o_bufD;
    float* dtbuf = ws + o_bufG;
    float* yf    = ws + o_bufH;
    float* xm    = ws + o_bufX;

    float* xbuf = xe;     // [16384][512]
    float* dbc  = out1;   // [16384][48]
    float* yo   = u;      // [16384][256]

    // 1. weight transposes
    k_prep<<<2688, 256, 0, stream>>>(w1, w2, win, xw, dtw, ow, ws);
    // 2. embedding gather -> xe [8][4096][256]
    k_embed<<<(Bn*L*64)/256, 256, 0, stream>>>(tok, emb, xe);
    // 3. conv1 + relu + pool -> out1 [8][2048][128]
    k_conv1_pool<<<dim3(L/32, Bn), 256, 0, stream>>>(xe, wt1, b1, out1);
    // 4. conv2 + relu -> u [8][2048][256]
    k_conv2<<<dim3(Lh/32, 2, Bn), 256, 0, stream>>>(out1, wt2, b2, u);
    // 5. in_proj -> xz [16384][1024]
    k_gemm<0><<<dim3(1024/64, M2/64), 256, 0, stream>>>(u, Dlat, wtin, nullptr, xz, M2, 1024, Dlat);
    // 6. depthwise conv + silu -> xbuf [16384][512]
    k_dwconv<<<(M2*128)/256, 256, 0, stream>>>(xz, wdw, bdw, xbuf);
    // 7. x_proj -> dbc [16384][48]
    k_gemm<0><<<dim3(1, M2/64), 256, 0, stream>>>(xbuf, Din, wtx, nullptr, dbc, M2, 48, Din);
    // 8. dt_proj + softplus -> dtbuf [16384][512]
    k_gemm<1><<<dim3(512/64, M2/64), 256, 0, stream>>>(dbc, 48, wtdt, dtb, dtbuf, M2, 512, 16);
    // 9. selective scan fused with skip & gate -> yf [16384][512]
    k_scan<<<256, 256, 0, stream>>>(dtbuf, xbuf, xz, dbc, alog, Dp, yf);
    // 10. out_proj -> yo [16384][256]
    k_gemm<0><<<dim3(256/64, M2/64), 256, 0, stream>>>(yf, Din, wtout, nullptr, yo, M2, 256, Din);
    // 11. mean over t
    hipMemsetAsync(xm, 0, Bn*Dlat*sizeof(float), stream);
    k_meanpart<<<Bn*32, 256, 0, stream>>>(yo, xm);
    // 12. fc -> logits [8][10]
    k_fc<<<1, 128, 0, stream>>>(xm, fcw, fcb, out);
}

// Round 5
// 841.746 us; speedup vs baseline: 1.4332x; 1.4332x over previous
//
#include <hip/hip_runtime.h>
#include <hip/hip_bf16.h>

// ---------------- problem constants ----------------
constexpr int Bn   = 8;
constexpr int L    = 4096;
constexpr int E    = 256;
constexpr int Lh   = 2048;   // after maxpool(2)
constexpr int C1n  = 128;
constexpr int Dlat = 256;
constexpr int Din  = 512;
constexpr int Nst  = 16;
constexpr int Dtr  = 16;
constexpr int M2   = Bn * Lh;   // 16384 rows for all mamba GEMMs
constexpr int NCH  = 32;        // scan chunks
constexpr int TC   = 64;        // timesteps per chunk

// ---------------- workspace layout (float offsets) ----------------
constexpr long o_wt1   = 0;                       // [5][256][128]
constexpr long o_wt2   = o_wt1  + 5L*256*128;     // [3][128][256]
constexpr long o_wtin  = o_wt2  + 3L*128*256;     // [256][1024]
constexpr long o_wtx   = o_wtin + 256L*1024;      // [512][48]
constexpr long o_wtdt  = o_wtx  + 512L*48;        // [16][512]
constexpr long o_wtout = o_wtdt + 16L*512;        // [512][256]
constexpr long o_endw  = o_wtout + 512L*256;      // = 688128
constexpr long o_bufA  = o_endw;                  // xe [8][4096][256] -> later x [8][2048][512]
constexpr long o_bufB  = o_bufA + (long)Bn*L*E;       // out1 [8][2048][128] -> later dbc [16384][48]
constexpr long o_bufC  = o_bufB + (long)Bn*Lh*C1n;    // u [16384][256] -> later hend+P -> later yo
constexpr long o_bufD  = o_bufC + (long)M2*Dlat;      // xz [16384][1024]
constexpr long o_bufG  = o_bufD + (long)M2*2*Din;     // dt [16384][512]
constexpr long o_bufH  = o_bufG + (long)M2*Din;       // y_final [16384][512]
constexpr long o_bufX  = o_bufH + (long)M2*Din;       // mean sums [8][256]
constexpr long o_hin   = o_bufX + (long)Bn*Dlat;      // hin [8][512][32][16]
constexpr long n_state = (long)Bn*Din*NCH*Nst;        // 2097152 floats

// ---------------- weight pre-transpose ----------------
__global__ void k_prep(const float* __restrict__ w1, const float* __restrict__ w2,
                       const float* __restrict__ win, const float* __restrict__ xw,
                       const float* __restrict__ dtw, const float* __restrict__ ow,
                       float* __restrict__ ws) {
    int idx = blockIdx.x * 256 + threadIdx.x;
    if (idx < 163840) {                       // wt1[k][c][o] = w1[o][c][k]
        int o = idx & 127; int rem = idx >> 7; int c = rem & 255; int k = rem >> 8;
        ws[o_wt1 + idx] = w1[(o*256 + c)*5 + k];
    } else if (idx < 262144) {                // wt2[k][c][o] = w2[o][c][k]
        int j = idx - 163840;
        int o = j & 255; int rem = j >> 8; int c = rem & 127; int k = rem >> 7;
        ws[o_wt2 + j] = w2[(o*128 + c)*3 + k];
    } else if (idx < 524288) {                // wtin[k][n] = win[n][k]
        int j = idx - 262144;
        int n_ = j & 1023; int k = j >> 10;
        ws[o_wtin + j] = win[n_*256 + k];
    } else if (idx < 548864) {                // wtx[k][n] = xw[n][k]
        int j = idx - 524288;
        int n_ = j % 48; int k = j / 48;
        ws[o_wtx + j] = xw[n_*512 + k];
    } else if (idx < 557056) {                // wtdt[k][n] = dtw[n][k]
        int j = idx - 548864;
        int n_ = j & 511; int k = j >> 9;
        ws[o_wtdt + j] = dtw[n_*16 + k];
    } else if (idx < 688128) {                // wtout[k][n] = ow[n][k]
        int j = idx - 557056;
        int n_ = j & 255; int k = j >> 8;
        ws[o_wtout + j] = ow[n_*512 + k];
    }
}

// ---------------- embedding gather ----------------
__global__ void k_embed(const int* __restrict__ tok, const float* __restrict__ emb,
                        float* __restrict__ xe) {
    int idx = blockIdx.x * 256 + threadIdx.x;     // float4 index
    int row = idx >> 6;                           // 64 float4 per row (E=256)
    int c4  = idx & 63;
    int t = tok[row];
    ((float4*)xe)[(long)row*64 + c4] = ((const float4*)emb)[(long)t*64 + c4];
}

// ---------------- conv1 (K=1280) + ReLU + maxpool(2) ----------------
// out1[b][tp][o] over [8][2048][128]
__global__ __launch_bounds__(256) void k_conv1_pool(const float* __restrict__ xe,
                                                    const float* __restrict__ wt1,
                                                    const float* __restrict__ b1,
                                                    float* __restrict__ out1) {
    __shared__ float As[32][33];
    __shared__ float Bs[32][128];
    int t0  = blockIdx.x * 32;
    int b   = blockIdx.y;
    int tid = threadIdx.x;
    int ti  = tid >> 5;    // 0..7 : 4 conv-time rows each
    int oj  = tid & 31;    // 0..31: 4 output channels each
    float acc[4][4] = {};
    for (int k = 0; k < 5; ++k) {
        for (int c0 = 0; c0 < 256; c0 += 32) {
            { // A tile: 32 time rows x 32 channels
                int tt = tid >> 3, q = tid & 7;
                int tg = t0 + tt + k - 2;
                float4 v = {0.f,0.f,0.f,0.f};
                if (tg >= 0 && tg < L)
                    v = *(const float4*)&xe[((long)b*L + tg)*E + c0 + q*4];
                As[tt][q*4+0] = v.x; As[tt][q*4+1] = v.y;
                As[tt][q*4+2] = v.z; As[tt][q*4+3] = v.w;
            }
            #pragma unroll
            for (int r = 0; r < 4; ++r) { // B tile: 32 c x 128 o
                int idx = tid + r*256;
                int cc = idx >> 5, o4 = idx & 31;
                *(float4*)&Bs[cc][o4*4] =
                    *(const float4*)&wt1[((long)(k*256 + c0 + cc))*128 + o4*4];
            }
            __syncthreads();
            #pragma unroll
            for (int kk = 0; kk < 32; ++kk) {
                float4 bv = *(float4*)&Bs[kk][oj*4];
                float a0 = As[ti*4+0][kk], a1 = As[ti*4+1][kk];
                float a2 = As[ti*4+2][kk], a3 = As[ti*4+3][kk];
                acc[0][0] += a0*bv.x; acc[0][1] += a0*bv.y; acc[0][2] += a0*bv.z; acc[0][3] += a0*bv.w;
                acc[1][0] += a1*bv.x; acc[1][1] += a1*bv.y; acc[1][2] += a1*bv.z; acc[1][3] += a1*bv.w;
                acc[2][0] += a2*bv.x; acc[2][1] += a2*bv.y; acc[2][2] += a2*bv.z; acc[2][3] += a2*bv.w;
                acc[3][0] += a3*bv.x; acc[3][1] += a3*bv.y; acc[3][2] += a3*bv.z; acc[3][3] += a3*bv.w;
            }
            __syncthreads();
        }
    }
    float4 bias = *(const float4*)&b1[oj*4];
    float r[4][4];
    #pragma unroll
    for (int i = 0; i < 4; ++i) {
        r[i][0] = fmaxf(acc[i][0] + bias.x, 0.f);
        r[i][1] = fmaxf(acc[i][1] + bias.y, 0.f);
        r[i][2] = fmaxf(acc[i][2] + bias.z, 0.f);
        r[i][3] = fmaxf(acc[i][3] + bias.w, 0.f);
    }
    float4 v0, v1;
    v0.x = fmaxf(r[0][0], r[1][0]); v0.y = fmaxf(r[0][1], r[1][1]);
    v0.z = fmaxf(r[0][2], r[1][2]); v0.w = fmaxf(r[0][3], r[1][3]);
    v1.x = fmaxf(r[2][0], r[3][0]); v1.y = fmaxf(r[2][1], r[3][1]);
    v1.z = fmaxf(r[2][2], r[3][2]); v1.w = fmaxf(r[2][3], r[3][3]);
    int tp0 = (t0 + ti*4) >> 1;
    *(float4*)&out1[((long)b*Lh + tp0    )*C1n + oj*4] = v0;
    *(float4*)&out1[((long)b*Lh + tp0 + 1)*C1n + oj*4] = v1;
}

// ---------------- conv2 (K=384) + ReLU ----------------
// u[b][t][o] over [8][2048][256]
__global__ __launch_bounds__(256) void k_conv2(const float* __restrict__ in,
                                               const float* __restrict__ wt2,
                                               const float* __restrict__ b2,
                                               float* __restrict__ out) {
    __shared__ float As[32][33];
    __shared__ float Bs[32][128];
    int t0 = blockIdx.x * 32;
    int o0 = blockIdx.y * 128;
    int b  = blockIdx.z;
    int tid = threadIdx.x;
    int ti  = tid >> 5;
    int oj  = tid & 31;
    float acc[4][4] = {};
    for (int k = 0; k < 3; ++k) {
        for (int c0 = 0; c0 < 128; c0 += 32) {
            {
                int tt = tid >> 3, q = tid & 7;
                int tg = t0 + tt + k - 1;
                float4 v = {0.f,0.f,0.f,0.f};
                if (tg >= 0 && tg < Lh)
                    v = *(const float4*)&in[((long)b*Lh + tg)*C1n + c0 + q*4];
                As[tt][q*4+0] = v.x; As[tt][q*4+1] = v.y;
                As[tt][q*4+2] = v.z; As[tt][q*4+3] = v.w;
            }
            #pragma unroll
            for (int r = 0; r < 4; ++r) {
                int idx = tid + r*256;
                int cc = idx >> 5, o4 = idx & 31;
                *(float4*)&Bs[cc][o4*4] =
                    *(const float4*)&wt2[((long)(k*128 + c0 + cc))*256 + o0 + o4*4];
            }
            __syncthreads();
            #pragma unroll
            for (int kk = 0; kk < 32; ++kk) {
                float4 bv = *(float4*)&Bs[kk][oj*4];
                float a0 = As[ti*4+0][kk], a1 = As[ti*4+1][kk];
                float a2 = As[ti*4+2][kk], a3 = As[ti*4+3][kk];
                acc[0][0] += a0*bv.x; acc[0][1] += a0*bv.y; acc[0][2] += a0*bv.z; acc[0][3] += a0*bv.w;
                acc[1][0] += a1*bv.x; acc[1][1] += a1*bv.y; acc[1][2] += a1*bv.z; acc[1][3] += a1*bv.w;
                acc[2][0] += a2*bv.x; acc[2][1] += a2*bv.y; acc[2][2] += a2*bv.z; acc[2][3] += a2*bv.w;
                acc[3][0] += a3*bv.x; acc[3][1] += a3*bv.y; acc[3][2] += a3*bv.z; acc[3][3] += a3*bv.w;
            }
            __syncthreads();
        }
    }
    float4 bias = *(const float4*)&b2[o0 + oj*4];
    #pragma unroll
    for (int i = 0; i < 4; ++i) {
        int t = t0 + ti*4 + i;
        float4 v;
        v.x = fmaxf(acc[i][0] + bias.x, 0.f);
        v.y = fmaxf(acc[i][1] + bias.y, 0.f);
        v.z = fmaxf(acc[i][2] + bias.z, 0.f);
        v.w = fmaxf(acc[i][3] + bias.w, 0.f);
        *(float4*)&out[((long)b*Lh + t)*Dlat + o0 + oj*4] = v;
    }
}

// ---------------- generic fp32 GEMM: out[M][N] = act(A[M][K(lda)] @ WT[K][N] + bias) ----------------
template<int ACT>   // 0 = none, 1 = softplus
__global__ __launch_bounds__(256) void k_gemm(const float* __restrict__ A, int lda,
                                              const float* __restrict__ WT,
                                              const float* __restrict__ bias,
                                              float* __restrict__ out,
                                              int M, int N, int K) {
    __shared__ float As[16][68];
    __shared__ float Bs[16][64];
    int n0 = blockIdx.x * 64, m0 = blockIdx.y * 64;
    int tid = threadIdx.x;
    int ti = tid >> 4, tj = tid & 15;
    float acc[4][4] = {};
    for (int k0 = 0; k0 < K; k0 += 16) {
        {
            int mm = tid >> 2, kq = tid & 3;
            float4 v = *(const float4*)&A[(long)(m0 + mm)*lda + k0 + kq*4];
            As[kq*4+0][mm] = v.x; As[kq*4+1][mm] = v.y;
            As[kq*4+2][mm] = v.z; As[kq*4+3][mm] = v.w;
        }
        {
            int kk = tid >> 4, n4 = tid & 15;
            float4 v = {0.f,0.f,0.f,0.f};
            if (n0 + n4*4 < N)
                v = *(const float4*)&WT[(long)(k0 + kk)*N + n0 + n4*4];
            *(float4*)&Bs[kk][n4*4] = v;
        }
        __syncthreads();
        #pragma unroll
        for (int kk = 0; kk < 16; ++kk) {
            float4 av = *(float4*)&As[kk][ti*4];
            float4 bv = *(float4*)&Bs[kk][tj*4];
            acc[0][0] += av.x*bv.x; acc[0][1] += av.x*bv.y; acc[0][2] += av.x*bv.z; acc[0][3] += av.x*bv.w;
            acc[1][0] += av.y*bv.x; acc[1][1] += av.y*bv.y; acc[1][2] += av.y*bv.z; acc[1][3] += av.y*bv.w;
            acc[2][0] += av.z*bv.x; acc[2][1] += av.z*bv.y; acc[2][2] += av.z*bv.z; acc[2][3] += av.z*bv.w;
            acc[3][0] += av.w*bv.x; acc[3][1] += av.w*bv.y; acc[3][2] += av.w*bv.z; acc[3][3] += av.w*bv.w;
        }
        __syncthreads();
    }
    if (n0 + tj*4 >= N) return;
    float4 bv = {0.f,0.f,0.f,0.f};
    if (bias) bv = *(const float4*)&bias[n0 + tj*4];
    #pragma unroll
    for (int i = 0; i < 4; ++i) {
        int m = m0 + ti*4 + i;
        float4 v;
        v.x = acc[i][0] + bv.x; v.y = acc[i][1] + bv.y;
        v.z = acc[i][2] + bv.z; v.w = acc[i][3] + bv.w;
        if (ACT == 1) {  // softplus
            v.x = (v.x > 20.f) ? v.x : log1pf(__expf(v.x));
            v.y = (v.y > 20.f) ? v.y : log1pf(__expf(v.y));
            v.z = (v.z > 20.f) ? v.z : log1pf(__expf(v.z));
            v.w = (v.w > 20.f) ? v.w : log1pf(__expf(v.w));
        }
        *(float4*)&out[(long)m*N + n0 + tj*4] = v;
    }
}

// ---------------- causal depthwise conv (k=4) + SiLU ----------------
__global__ void k_dwconv(const float* __restrict__ xz, const float* __restrict__ wdw,
                         const float* __restrict__ bdw, float* __restrict__ xout) {
    int idx = blockIdx.x * 256 + threadIdx.x;       // (b,t,d4)
    int d4 = idx & 127; int rem = idx >> 7;
    int t = rem & 2047; int b = rem >> 11;
    int d0 = d4 * 4;
    float4 acc = *(const float4*)&bdw[d0];
    #pragma unroll
    for (int k = 0; k < 4; ++k) {
        int tt = t - 3 + k;
        if (tt >= 0) {
            float4 v = *(const float4*)&xz[((long)(b*Lh + tt))*1024 + d0];
            acc.x += v.x * wdw[(d0+0)*4 + k];
            acc.y += v.y * wdw[(d0+1)*4 + k];
            acc.z += v.z * wdw[(d0+2)*4 + k];
            acc.w += v.w * wdw[(d0+3)*4 + k];
        }
    }
    acc.x = acc.x / (1.f + __expf(-acc.x));
    acc.y = acc.y / (1.f + __expf(-acc.y));
    acc.z = acc.z / (1.f + __expf(-acc.z));
    acc.w = acc.w / (1.f + __expf(-acc.w));
    *(float4*)&xout[(long)idx * 4] = acc;
}

// ---------------- chunked selective scan ----------------
// Phase A: per-chunk local scan (h starts at 0) -> hend, P per (b,d,chunk,n)
__global__ __launch_bounds__(256) void k_scan_a(const float* __restrict__ dt,
                                                const float* __restrict__ x,
                                                const float* __restrict__ dbc,
                                                const float* __restrict__ A_log,
                                                float* __restrict__ hend,
                                                float* __restrict__ Pbuf) {
    __shared__ float dt_s[TC][16], x_s[TC][16], Bs_[TC][16];
    int c  = blockIdx.x;          // chunk
    int d0 = blockIdx.y * 16;     // channel group
    int b  = blockIdx.z;
    int tid = threadIdx.x;
    int lane = tid & 63; int wave = tid >> 6;
    int g = lane >> 4; int n = lane & 15;
    int ch = wave * 4 + g; int d = d0 + ch;
    float Areg = -__expf(A_log[d*16 + n]);
    int row = tid >> 2, q = (tid & 3) * 4;
    long base = (long)b*Lh + c*TC + row;
    *(float4*)&dt_s[row][q] = *(const float4*)&dt[base*512 + d0 + q];
    *(float4*)&x_s[row][q]  = *(const float4*)&x[base*512 + d0 + q];
    *(float4*)&Bs_[row][q]  = *(const float4*)&dbc[base*48 + 16 + q];
    __syncthreads();
    float h = 0.f, sd = 0.f;
    #pragma unroll 8
    for (int tt = 0; tt < TC; ++tt) {
        float dtv = dt_s[tt][ch];
        float dA  = __expf(dtv * Areg);
        h = h * dA + dtv * x_s[tt][ch] * Bs_[tt][n];
        sd += dtv;
    }
    long o = (((long)b*Din + d)*NCH + c)*Nst + n;
    hend[o] = h;
    Pbuf[o] = __expf(Areg * sd);
}

// Phase B: serial combine over chunks -> carry-in hin per (b,d,chunk,n)
__global__ void k_scan_b(const float* __restrict__ hend, const float* __restrict__ Pbuf,
                         float* __restrict__ hin) {
    int idx = blockIdx.x * 256 + threadIdx.x;   // (b,d,n): 8*512*16 = 65536
    int n = idx & 15; int d = (idx >> 4) & 511; int b = idx >> 13;
    long base = (((long)b*Din + d)*NCH)*Nst + n;
    float h = 0.f;
    for (int c = 0; c < NCH; ++c) {
        hin[base + c*Nst] = h;
        h = hend[base + c*Nst] + Pbuf[base + c*Nst] * h;
    }
}

// Phase C: per-chunk scan with carry-in; y + Dp skip + silu(z) gate -> yf
__global__ __launch_bounds__(256) void k_scan_c(const float* __restrict__ dt,
                                                const float* __restrict__ x,
                                                const float* __restrict__ xz,
                                                const float* __restrict__ dbc,
                                                const float* __restrict__ A_log,
                                                const float* __restrict__ Dp,
                                                const float* __restrict__ hin,
                                                float* __restrict__ yf) {
    __shared__ float dt_s[TC][16], x_s[TC][16], z_s[TC][16];
    __shared__ float Bs_[TC][16], Cs_[TC][16], ys[TC][16];
    int c  = blockIdx.x;
    int d0 = blockIdx.y * 16;
    int b  = blockIdx.z;
    int tid = threadIdx.x;
    int lane = tid & 63; int wave = tid >> 6;
    int g = lane >> 4; int n = lane & 15;
    int ch = wave * 4 + g; int d = d0 + ch;
    float Areg = -__expf(A_log[d*16 + n]);
    float Dpv  = Dp[d];
    int row = tid >> 2, q = (tid & 3) * 4;
    long base = (long)b*Lh + c*TC + row;
    *(float4*)&dt_s[row][q] = *(const float4*)&dt[base*512 + d0 + q];
    *(float4*)&x_s[row][q]  = *(const float4*)&x[base*512 + d0 + q];
    *(float4*)&z_s[row][q]  = *(const float4*)&xz[base*1024 + 512 + d0 + q];
    *(float4*)&Bs_[row][q]  = *(const float4*)&dbc[base*48 + 16 + q];
    *(float4*)&Cs_[row][q]  = *(const float4*)&dbc[base*48 + 32 + q];
    __syncthreads();
    float h = hin[(((long)b*Din + d)*NCH + c)*Nst + n];
    for (int tt = 0; tt < TC; ++tt) {
        float dtv = dt_s[tt][ch];
        float xv  = x_s[tt][ch];
        float bvv = Bs_[tt][n];
        float cv  = Cs_[tt][n];
        float dA  = __expf(dtv * Areg);
        h = h * dA + dtv * xv * bvv;
        float p = h * cv;
        p += __shfl_xor(p, 1);
        p += __shfl_xor(p, 2);
        p += __shfl_xor(p, 4);
        p += __shfl_xor(p, 8);
        if (n == 0) {
            float zv = z_s[tt][ch];
            float sz = zv / (1.f + __expf(-zv));
            ys[tt][ch] = (p + xv * Dpv) * sz;
        }
    }
    __syncthreads();
    *(float4*)&yf[base*512 + d0 + q] = *(float4*)&ys[row][q];
}

// ---------------- mean over t (partial sums + atomics) ----------------
__global__ void k_meanpart(const float* __restrict__ yo, float* __restrict__ xm) {
    int chunk = blockIdx.x & 31;
    int b = blockIdx.x >> 5;
    int c = threadIdx.x;
    float s = 0.f;
    int t0 = chunk * 64;
    #pragma unroll 4
    for (int t = t0; t < t0 + 64; ++t)
        s += yo[((long)b*Lh + t)*Dlat + c];
    atomicAdd(&xm[b*Dlat + c], s);
}

// ---------------- final fc ----------------
__global__ void k_fc(const float* __restrict__ xm, const float* __restrict__ fcw,
                     const float* __restrict__ fcb, float* __restrict__ out) {
    int tid = threadIdx.x;
    if (tid < 80) {
        int b = tid / 10, o = tid % 10;
        float s = 0.f;
        for (int c = 0; c < Dlat; ++c)
            s += xm[b*Dlat + c] * fcw[o*Dlat + c];
        out[tid] = s * (1.f / 2048.f) + fcb[o];
    }
}

extern "C" void kernel_launch(void* const* d_in, const int* in_sizes, int n_in,
                              void* d_out, int out_size, void* d_ws, size_t ws_size,
                              hipStream_t stream) {
    const int*   tok  = (const int*)d_in[0];
    const float* emb  = (const float*)d_in[1];
    const float* w1   = (const float*)d_in[2];
    const float* b1   = (const float*)d_in[3];
    const float* w2   = (const float*)d_in[4];
    const float* b2   = (const float*)d_in[5];
    const float* win  = (const float*)d_in[6];
    const float* wdw  = (const float*)d_in[7];
    const float* bdw  = (const float*)d_in[8];
    const float* xw   = (const float*)d_in[9];
    const float* dtw  = (const float*)d_in[10];
    const float* dtb  = (const float*)d_in[11];
    const float* alog = (const float*)d_in[12];
    const float* Dp   = (const float*)d_in[13];
    const float* ow   = (const float*)d_in[14];
    const float* fcw  = (const float*)d_in[15];
    const float* fcb  = (const float*)d_in[16];
    float* ws  = (float*)d_ws;
    float* out = (float*)d_out;

    float* wt1   = ws + o_wt1;
    float* wt2   = ws + o_wt2;
    float* wtin  = ws + o_wtin;
    float* wtx   = ws + o_wtx;
    float* wtdt  = ws + o_wtdt;
    float* wtout = ws + o_wtout;
    float* xe    = ws + o_bufA;   // later reused as x (post dwconv+silu)
    float* out1  = ws + o_bufB;   // later reused as dbc
    float* u     = ws + o_bufC;   // later reused as hend+P, then yo
    float* xz    = ws + o_bufD;
    float* dtbuf = ws + o_bufG;
    float* yf    = ws + o_bufH;
    float* xm    = ws + o_bufX;

    float* xbuf = xe;             // [16384][512]
    float* dbc  = out1;           // [16384][48]
    float* yo   = u;              // [16384][256]
    float* hend = u;              // [8][512][32][16] (2.1M floats, bufC is 4.2M)
    float* Pbuf = u + n_state;    // [8][512][32][16]
    float* hin  = ws + o_hin;     // [8][512][32][16]

    // 1. weight transposes
    k_prep<<<2688, 256, 0, stream>>>(w1, w2, win, xw, dtw, ow, ws);
    // 2. embedding gather -> xe [8][4096][256]
    k_embed<<<(Bn*L*64)/256, 256, 0, stream>>>(tok, emb, xe);
    // 3. conv1 + relu + pool -> out1 [8][2048][128]
    k_conv1_pool<<<dim3(L/32, Bn), 256, 0, stream>>>(xe, wt1, b1, out1);
    // 4. conv2 + relu -> u [8][2048][256]
    k_conv2<<<dim3(Lh/32, 2, Bn), 256, 0, stream>>>(out1, wt2, b2, u);
    // 5. in_proj -> xz [16384][1024]
    k_gemm<0><<<dim3(1024/64, M2/64), 256, 0, stream>>>(u, Dlat, wtin, nullptr, xz, M2, 1024, Dlat);
    // 6. depthwise conv + silu -> xbuf [16384][512]
    k_dwconv<<<(M2*128)/256, 256, 0, stream>>>(xz, wdw, bdw, xbuf);
    // 7. x_proj -> dbc [16384][48]
    k_gemm<0><<<dim3(1, M2/64), 256, 0, stream>>>(xbuf, Din, wtx, nullptr, dbc, M2, 48, Din);
    // 8. dt_proj + softplus -> dtbuf [16384][512]
    k_gemm<1><<<dim3(512/64, M2/64), 256, 0, stream>>>(dbc, 48, wtdt, dtb, dtbuf, M2, 512, 16);
    // 9. chunked selective scan fused with skip & gate -> yf [16384][512]
    k_scan_a<<<dim3(NCH, Din/16, Bn), 256, 0, stream>>>(dtbuf, xbuf, dbc, alog, hend, Pbuf);
    k_scan_b<<<(Bn*Din*Nst)/256, 256, 0, stream>>>(hend, Pbuf, hin);
    k_scan_c<<<dim3(NCH, Din/16, Bn), 256, 0, stream>>>(dtbuf, xbuf, xz, dbc, alog, Dp, hin, yf);
    // 10. out_proj -> yo [16384][256]  (bufC free again after scan)
    k_gemm<0><<<dim3(256/64, M2/64), 256, 0, stream>>>(yf, Din, wtout, nullptr, yo, M2, 256, Din);
    // 11. mean over t
    hipMemsetAsync(xm, 0, Bn*Dlat*sizeof(float), stream);
    k_meanpart<<<Bn*32, 256, 0, stream>>>(yo, xm);
    // 12. fc -> logits [8][10]
    k_fc<<<1, 128, 0, stream>>>(xm, fcw, fcb, out);
}

// Round 6
// 626.815 us; speedup vs baseline: 1.9246x; 1.3429x over previous
//
#include <hip/hip_runtime.h>
#include <hip/hip_bf16.h>

// ---------------- problem constants ----------------
constexpr int Bn   = 8;
constexpr int L    = 4096;
constexpr int E    = 256;
constexpr int Lh   = 2048;
constexpr int C1n  = 128;
constexpr int Dlat = 256;
constexpr int Din  = 512;
constexpr int Nst  = 16;
constexpr int M2   = Bn * Lh;   // 16384
constexpr int NCH  = 32;        // scan chunks
constexpr int TC   = 64;        // timesteps per chunk

// ---------------- workspace layout (float offsets) ----------------
constexpr long o_wtx   = 0;                         // [512][48] fp32
constexpr long o_wtdt  = o_wtx  + 512L*48;          // [16][512] fp32
constexpr long o_bf    = o_wtdt + 16L*512;          // bf16 weights region (shorts)
//   shorts: wt1t [128][1280], wt2t [256][384], wtint [1024][256] = 524288 shorts
constexpr long o_xeb   = o_bf    + 524288/2;        // xe bf16 [8][4100][256] padded
constexpr long o_out1b = o_xeb   + (8L*4100*256)/2; // out1 bf16 [8][2050][128] padded
constexpr long o_ub    = o_out1b + (8L*2050*128)/2; // u bf16 [16384][256]
constexpr long o_xz    = o_ub    + (16384L*256)/2;  // fp32 [16384][1024]
constexpr long o_xbuf  = o_xz    + 16384L*1024;     // fp32 [16384][512]
constexpr long o_dbc   = o_xbuf  + 16384L*512;      // fp32 [16384][48]
constexpr long o_dt    = o_dbc   + 16384L*48;       // fp32 [16384][512]
constexpr long o_yf    = o_dt    + 16384L*512;      // fp32 [16384][512]
constexpr long o_hend  = o_yf    + 16384L*512;
constexpr long o_P     = o_hend  + 8L*512*NCH*16;
constexpr long o_hin   = o_P     + 8L*512*NCH*16;
constexpr long o_ym    = o_hin   + 8L*512*NCH*16;   // fp32 [8][512]

typedef __attribute__((ext_vector_type(8))) short bf8_t;
typedef __attribute__((ext_vector_type(4))) float f4_t;

__device__ inline short f2bf(float f) {
    unsigned int u = __float_as_uint(f);
    unsigned int r = (u + 0x7FFFu + ((u >> 16) & 1u)) >> 16;
    return (short)r;
}

// ---------------- weight prep: fp32 transposes + bf16 [N][K] transposes ----------------
__global__ void k_prep(const float* __restrict__ w1, const float* __restrict__ w2,
                       const float* __restrict__ win, const float* __restrict__ xw,
                       const float* __restrict__ dtw, float* __restrict__ ws) {
    int idx = blockIdx.x * 256 + threadIdx.x;
    if (idx < 24576) {                        // wtx[k][n] = xw[n][k]  (fp32)
        int n_ = idx % 48; int k = idx / 48;
        ws[o_wtx + idx] = xw[n_*512 + k];
    } else if (idx < 32768) {                 // wtdt[k][n] = dtw[n][k] (fp32)
        int j = idx - 24576;
        int n_ = j & 511; int k = j >> 9;
        ws[o_wtdt + j] = dtw[n_*16 + k];
    } else if (idx < 557056) {                // bf16 region
        int j = idx - 32768;
        short* wsS = (short*)(ws + o_bf);
        if (j < 163840) {                     // wt1t[n][s*256+c] = w1[n][c][s]
            int n_ = j / 1280; int r = j - n_*1280; int s = r >> 8; int c = r & 255;
            wsS[j] = f2bf(w1[(n_*256 + c)*5 + s]);
        } else if (j < 262144) {              // wt2t[n][s*128+c] = w2[n][c][s]
            int jj = j - 163840;
            int n_ = jj / 384; int r = jj - n_*384; int s = r >> 7; int c = r & 127;
            wsS[j] = f2bf(w2[(n_*128 + c)*3 + s]);
        } else {                              // wtint[n][k] = win[n][k]
            int jj = j - 262144;
            int n_ = jj >> 8; int k = jj & 255;
            wsS[j] = f2bf(win[n_*256 + k]);
        }
    }
}

// ---------------- embedding gather -> padded bf16 [8][4100][256] ----------------
__global__ void k_embed(const int* __restrict__ tok, const float* __restrict__ emb,
                        short* __restrict__ xeb) {
    int idx = blockIdx.x * 256 + threadIdx.x;   // 8*4100*32 = 1,049,600 threads
    int r = idx >> 5;
    int c8 = (idx & 31) << 3;
    int b = r / 4100; int tr = r - b*4100;
    bf8_t v = {0,0,0,0,0,0,0,0};
    if (tr >= 2 && tr < 4098) {
        int t = tok[b*4096 + tr - 2];
        const float* e = emb + (long)t*256 + c8;
        #pragma unroll
        for (int i = 0; i < 8; ++i) v[i] = f2bf(e[i]);
    }
    *(bf8_t*)&xeb[(long)r*256 + c8] = v;
}

// ---------------- zero pad rows of out1b ----------------
__global__ void k_zpad(short* __restrict__ out1b) {
    int i = threadIdx.x;
    for (int j = i; j < 2048; j += 256) {
        int b = j >> 8; int rsel = (j >> 7) & 1; int c = j & 127;
        long row = (long)b*2050 + (rsel ? 2049 : 0);
        out1b[row*128 + c] = 0;
    }
}

// ---------------- MFMA GEMM (conv-as-GEMM + plain) ----------------
// Block: 32 rows x 128 cols, 4 waves (32 cols each), 2x2 16x16 frag tiles/wave.
// A bf16 [rows][ars] (pre-padded for convs); Bt bf16 [N][ktot].
// EPI: 0 = fp32 store; 1 = bias+relu -> bf16; 2 = bias+relu+maxpool2 -> bf16 (padded out)
template<int SHIFTS, int CPS, int EPI>
__global__ __launch_bounds__(256) void k_mgemm(const short* __restrict__ A, int ars, long batchA,
                                               const short* __restrict__ Bt, int ktot,
                                               const float* __restrict__ bias,
                                               short* __restrict__ outB, float* __restrict__ outF,
                                               int ors, long batchOut) {
    constexpr int KSTEPS = SHIFTS * CPS;
    int l = threadIdx.x & 63, w = threadIdx.x >> 6;
    int m0 = blockIdx.x * 32;
    int n0 = blockIdx.y * 128 + w * 32;
    long zA = (long)blockIdx.z * batchA;
    long zO = (long)blockIdx.z * batchOut;

    const short* ap = A + zA + (long)(m0 + (l & 15)) * ars + ((l >> 4) << 3);
    const short* bp = Bt + (long)(n0 + (l & 15)) * ktot + ((l >> 4) << 3);

    f4_t acc[2][2];
    #pragma unroll
    for (int i = 0; i < 2; ++i)
        #pragma unroll
        for (int j = 0; j < 2; ++j) acc[i][j] = (f4_t){0.f, 0.f, 0.f, 0.f};

    for (int ks = 0; ks < KSTEPS; ++ks) {
        int shift = ks / CPS;
        int c0 = (ks % CPS) * 32;
        const short* a = ap + (long)shift * ars + c0;
        bf8_t a0 = *(const bf8_t*)a;
        bf8_t a1 = *(const bf8_t*)(a + 16 * ars);
        const short* bq = bp + ks * 32;
        bf8_t b0 = *(const bf8_t*)bq;
        bf8_t b1 = *(const bf8_t*)(bq + 16 * ktot);
        acc[0][0] = __builtin_amdgcn_mfma_f32_16x16x32_bf16(a0, b0, acc[0][0], 0, 0, 0);
        acc[0][1] = __builtin_amdgcn_mfma_f32_16x16x32_bf16(a0, b1, acc[0][1], 0, 0, 0);
        acc[1][0] = __builtin_amdgcn_mfma_f32_16x16x32_bf16(a1, b0, acc[1][0], 0, 0, 0);
        acc[1][1] = __builtin_amdgcn_mfma_f32_16x16x32_bf16(a1, b1, acc[1][1], 0, 0, 0);
    }

    #pragma unroll
    for (int mt = 0; mt < 2; ++mt)
        #pragma unroll
        for (int nt = 0; nt < 2; ++nt) {
            f4_t c = acc[mt][nt];
            int col = n0 + nt * 16 + (l & 15);
            int r0 = m0 + mt * 16 + ((l >> 4) << 2);
            if constexpr (EPI == 0) {
                #pragma unroll
                for (int j = 0; j < 4; ++j)
                    outF[zO + (long)(r0 + j) * ors + col] = c[j];
            } else if constexpr (EPI == 1) {
                float bv = bias[col];
                #pragma unroll
                for (int j = 0; j < 4; ++j)
                    outB[zO + (long)(r0 + j) * ors + col] = f2bf(fmaxf(c[j] + bv, 0.f));
            } else {
                float bv = bias[col];
                float p0 = fmaxf(fmaxf(c[0], c[1]) + bv, 0.f);
                float p1 = fmaxf(fmaxf(c[2], c[3]) + bv, 0.f);
                int tp = r0 >> 1;
                outB[zO + (long)(tp + 1) * ors + col] = f2bf(p0);
                outB[zO + (long)(tp + 2) * ors + col] = f2bf(p1);
            }
        }
}

// ---------------- fp32 GEMM (x_proj / dt_proj path, precision-sensitive) ----------------
template<int ACT>   // 0 = none, 1 = softplus
__global__ __launch_bounds__(256) void k_gemm(const float* __restrict__ A, int lda,
                                              const float* __restrict__ WT,
                                              const float* __restrict__ bias,
                                              float* __restrict__ out,
                                              int M, int N, int K) {
    __shared__ float As[16][68];
    __shared__ float Bs[16][64];
    int n0 = blockIdx.x * 64, m0 = blockIdx.y * 64;
    int tid = threadIdx.x;
    int ti = tid >> 4, tj = tid & 15;
    float acc[4][4] = {};
    for (int k0 = 0; k0 < K; k0 += 16) {
        {
            int mm = tid >> 2, kq = tid & 3;
            float4 v = *(const float4*)&A[(long)(m0 + mm)*lda + k0 + kq*4];
            As[kq*4+0][mm] = v.x; As[kq*4+1][mm] = v.y;
            As[kq*4+2][mm] = v.z; As[kq*4+3][mm] = v.w;
        }
        {
            int kk = tid >> 4, n4 = tid & 15;
            float4 v = {0.f,0.f,0.f,0.f};
            if (n0 + n4*4 < N)
                v = *(const float4*)&WT[(long)(k0 + kk)*N + n0 + n4*4];
            *(float4*)&Bs[kk][n4*4] = v;
        }
        __syncthreads();
        #pragma unroll
        for (int kk = 0; kk < 16; ++kk) {
            float4 av = *(float4*)&As[kk][ti*4];
            float4 bv = *(float4*)&Bs[kk][tj*4];
            acc[0][0] += av.x*bv.x; acc[0][1] += av.x*bv.y; acc[0][2] += av.x*bv.z; acc[0][3] += av.x*bv.w;
            acc[1][0] += av.y*bv.x; acc[1][1] += av.y*bv.y; acc[1][2] += av.y*bv.z; acc[1][3] += av.y*bv.w;
            acc[2][0] += av.z*bv.x; acc[2][1] += av.z*bv.y; acc[2][2] += av.z*bv.z; acc[2][3] += av.z*bv.w;
            acc[3][0] += av.w*bv.x; acc[3][1] += av.w*bv.y; acc[3][2] += av.w*bv.z; acc[3][3] += av.w*bv.w;
        }
        __syncthreads();
    }
    if (n0 + tj*4 >= N) return;
    float4 bv = {0.f,0.f,0.f,0.f};
    if (bias) bv = *(const float4*)&bias[n0 + tj*4];
    #pragma unroll
    for (int i = 0; i < 4; ++i) {
        int m = m0 + ti*4 + i;
        float4 v;
        v.x = acc[i][0] + bv.x; v.y = acc[i][1] + bv.y;
        v.z = acc[i][2] + bv.z; v.w = acc[i][3] + bv.w;
        if (ACT == 1) {
            v.x = (v.x > 20.f) ? v.x : log1pf(__expf(v.x));
            v.y = (v.y > 20.f) ? v.y : log1pf(__expf(v.y));
            v.z = (v.z > 20.f) ? v.z : log1pf(__expf(v.z));
            v.w = (v.w > 20.f) ? v.w : log1pf(__expf(v.w));
        }
        *(float4*)&out[(long)m*N + n0 + tj*4] = v;
    }
}

// ---------------- causal depthwise conv (k=4) + SiLU ----------------
__global__ void k_dwconv(const float* __restrict__ xz, const float* __restrict__ wdw,
                         const float* __restrict__ bdw, float* __restrict__ xout) {
    int idx = blockIdx.x * 256 + threadIdx.x;
    int d4 = idx & 127; int rem = idx >> 7;
    int t = rem & 2047; int b = rem >> 11;
    int d0 = d4 * 4;
    float4 acc = *(const float4*)&bdw[d0];
    #pragma unroll
    for (int k = 0; k < 4; ++k) {
        int tt = t - 3 + k;
        if (tt >= 0) {
            float4 v = *(const float4*)&xz[((long)(b*Lh + tt))*1024 + d0];
            acc.x += v.x * wdw[(d0+0)*4 + k];
            acc.y += v.y * wdw[(d0+1)*4 + k];
            acc.z += v.z * wdw[(d0+2)*4 + k];
            acc.w += v.w * wdw[(d0+3)*4 + k];
        }
    }
    acc.x = acc.x / (1.f + __expf(-acc.x));
    acc.y = acc.y / (1.f + __expf(-acc.y));
    acc.z = acc.z / (1.f + __expf(-acc.z));
    acc.w = acc.w / (1.f + __expf(-acc.w));
    *(float4*)&xout[(long)idx * 4] = acc;
}

// ---------------- chunked selective scan ----------------
__global__ __launch_bounds__(256) void k_scan_a(const float* __restrict__ dt,
                                                const float* __restrict__ x,
                                                const float* __restrict__ dbc,
                                                const float* __restrict__ A_log,
                                                float* __restrict__ hend,
                                                float* __restrict__ Pbuf) {
    __shared__ float dt_s[TC][16], x_s[TC][16], Bs_[TC][16];
    int c  = blockIdx.x;
    int d0 = blockIdx.y * 16;
    int b  = blockIdx.z;
    int tid = threadIdx.x;
    int lane = tid & 63; int wave = tid >> 6;
    int g = lane >> 4; int n = lane & 15;
    int ch = wave * 4 + g; int d = d0 + ch;
    float Areg = -__expf(A_log[d*16 + n]);
    int row = tid >> 2, q = (tid & 3) * 4;
    long base = (long)b*Lh + c*TC + row;
    *(float4*)&dt_s[row][q] = *(const float4*)&dt[base*512 + d0 + q];
    *(float4*)&x_s[row][q]  = *(const float4*)&x[base*512 + d0 + q];
    *(float4*)&Bs_[row][q]  = *(const float4*)&dbc[base*48 + 16 + q];
    __syncthreads();
    float h = 0.f, sd = 0.f;
    #pragma unroll 8
    for (int tt = 0; tt < TC; ++tt) {
        float dtv = dt_s[tt][ch];
        float dA  = __expf(dtv * Areg);
        h = h * dA + dtv * x_s[tt][ch] * Bs_[tt][n];
        sd += dtv;
    }
    long o = (((long)b*Din + d)*NCH + c)*Nst + n;
    hend[o] = h;
    Pbuf[o] = __expf(Areg * sd);
}

__global__ void k_scan_b(const float* __restrict__ hend, const float* __restrict__ Pbuf,
                         float* __restrict__ hin) {
    int idx = blockIdx.x * 256 + threadIdx.x;
    int n = idx & 15; int d = (idx >> 4) & 511; int b = idx >> 13;
    long base = (((long)b*Din + d)*NCH)*Nst + n;
    float h = 0.f;
    for (int c = 0; c < NCH; ++c) {
        hin[base + c*Nst] = h;
        h = hend[base + c*Nst] + Pbuf[base + c*Nst] * h;
    }
}

__global__ __launch_bounds__(256) void k_scan_c(const float* __restrict__ dt,
                                                const float* __restrict__ x,
                                                const float* __restrict__ xz,
                                                const float* __restrict__ dbc,
                                                const float* __restrict__ A_log,
                                                const float* __restrict__ Dp,
                                                const float* __restrict__ hin,
                                                float* __restrict__ yf) {
    __shared__ float dt_s[TC][16], x_s[TC][16], z_s[TC][16];
    __shared__ float Bs_[TC][16], Cs_[TC][16], ys[TC][16];
    int c  = blockIdx.x;
    int d0 = blockIdx.y * 16;
    int b  = blockIdx.z;
    int tid = threadIdx.x;
    int lane = tid & 63; int wave = tid >> 6;
    int g = lane >> 4; int n = lane & 15;
    int ch = wave * 4 + g; int d = d0 + ch;
    float Areg = -__expf(A_log[d*16 + n]);
    float Dpv  = Dp[d];
    int row = tid >> 2, q = (tid & 3) * 4;
    long base = (long)b*Lh + c*TC + row;
    *(float4*)&dt_s[row][q] = *(const float4*)&dt[base*512 + d0 + q];
    *(float4*)&x_s[row][q]  = *(const float4*)&x[base*512 + d0 + q];
    *(float4*)&z_s[row][q]  = *(const float4*)&xz[base*1024 + 512 + d0 + q];
    *(float4*)&Bs_[row][q]  = *(const float4*)&dbc[base*48 + 16 + q];
    *(float4*)&Cs_[row][q]  = *(const float4*)&dbc[base*48 + 32 + q];
    __syncthreads();
    float h = hin[(((long)b*Din + d)*NCH + c)*Nst + n];
    for (int tt = 0; tt < TC; ++tt) {
        float dtv = dt_s[tt][ch];
        float xv  = x_s[tt][ch];
        float bvv = Bs_[tt][n];
        float cv  = Cs_[tt][n];
        float dA  = __expf(dtv * Areg);
        h = h * dA + dtv * xv * bvv;
        float p = h * cv;
        p += __shfl_xor(p, 1);
        p += __shfl_xor(p, 2);
        p += __shfl_xor(p, 4);
        p += __shfl_xor(p, 8);
        if (n == 0) {
            float zv = z_s[tt][ch];
            float sz = zv / (1.f + __expf(-zv));
            ys[tt][ch] = (p + xv * Dpv) * sz;
        }
    }
    __syncthreads();
    *(float4*)&yf[base*512 + d0 + q] = *(float4*)&ys[row][q];
}

// ---------------- column mean of yf -> ym[8][512] (sum; scaled later) ----------------
__global__ void k_mean2(const float* __restrict__ yf, float* __restrict__ ym) {
    int b = blockIdx.x; int half = blockIdx.y; int tc = blockIdx.z;
    int d = half * 256 + threadIdx.x;
    float s = 0.f;
    int t0 = tc * 128;
    #pragma unroll 4
    for (int t = t0; t < t0 + 128; ++t)
        s += yf[((long)b*Lh + t)*512 + d];
    atomicAdd(&ym[b*512 + d], s);
}

// ---------------- tail: xm = (ym/2048) @ ow^T ; logits = xm @ fcw^T + fcb ----------------
__global__ void k_tail(const float* __restrict__ ym, const float* __restrict__ ow,
                       const float* __restrict__ fcw, const float* __restrict__ fcb,
                       float* __restrict__ out) {
    __shared__ float yls[512];
    __shared__ float xs[256];
    int b = blockIdx.x, c = threadIdx.x;
    yls[c] = ym[b*512 + c];
    yls[c + 256] = ym[b*512 + 256 + c];
    __syncthreads();
    float s = 0.f;
    for (int d = 0; d < 512; ++d) s += yls[d] * ow[c*512 + d];
    xs[c] = s * (1.f / 2048.f);
    __syncthreads();
    if (c < 10) {
        float t = fcb[c];
        for (int k = 0; k < 256; ++k) t += xs[k] * fcw[c*256 + k];
        out[b*10 + c] = t;
    }
}

extern "C" void kernel_launch(void* const* d_in, const int* in_sizes, int n_in,
                              void* d_out, int out_size, void* d_ws, size_t ws_size,
                              hipStream_t stream) {
    const int*   tok  = (const int*)d_in[0];
    const float* emb  = (const float*)d_in[1];
    const float* w1   = (const float*)d_in[2];
    const float* b1   = (const float*)d_in[3];
    const float* w2   = (const float*)d_in[4];
    const float* b2   = (const float*)d_in[5];
    const float* win  = (const float*)d_in[6];
    const float* wdw  = (const float*)d_in[7];
    const float* bdw  = (const float*)d_in[8];
    const float* xw   = (const float*)d_in[9];
    const float* dtw  = (const float*)d_in[10];
    const float* dtb  = (const float*)d_in[11];
    const float* alog = (const float*)d_in[12];
    const float* Dp   = (const float*)d_in[13];
    const float* ow   = (const float*)d_in[14];
    const float* fcw  = (const float*)d_in[15];
    const float* fcb  = (const float*)d_in[16];
    float* ws  = (float*)d_ws;
    float* out = (float*)d_out;

    float* wtx   = ws + o_wtx;
    float* wtdt  = ws + o_wtdt;
    short* wt1t  = (short*)(ws + o_bf);
    short* wt2t  = wt1t + 163840;
    short* wtint = wt2t + 98304;
    short* xeb   = (short*)(ws + o_xeb);
    short* out1b = (short*)(ws + o_out1b);
    short* ub    = (short*)(ws + o_ub);
    float* xz    = ws + o_xz;
    float* xbuf  = ws + o_xbuf;
    float* dbc   = ws + o_dbc;
    float* dtbuf = ws + o_dt;
    float* yf    = ws + o_yf;
    float* hend  = ws + o_hend;
    float* Pbuf  = ws + o_P;
    float* hin   = ws + o_hin;
    float* ym    = ws + o_ym;

    // 1. weight prep
    k_prep<<<2176, 256, 0, stream>>>(w1, w2, win, xw, dtw, ws);
    // 2. embedding -> padded bf16 xe [8][4100][256]
    k_embed<<<4100, 256, 0, stream>>>(tok, emb, xeb);
    // 3. zero pad rows of out1b
    k_zpad<<<1, 256, 0, stream>>>(out1b);
    // 4. conv1 (K=1280) + relu + pool -> out1b bf16 [8][2050][128]
    k_mgemm<5, 8, 2><<<dim3(128, 1, 8), 256, 0, stream>>>(
        xeb, 256, 4100L*256, wt1t, 1280, b1, out1b, nullptr, 128, 2050L*128);
    // 5. conv2 (K=384) + relu -> ub bf16 [16384][256]
    k_mgemm<3, 4, 1><<<dim3(64, 2, 8), 256, 0, stream>>>(
        out1b, 128, 2050L*128, wt2t, 384, b2, ub, nullptr, 256, 2048L*256);
    // 6. in_proj (K=256) -> xz fp32 [16384][1024]
    k_mgemm<1, 8, 0><<<dim3(512, 8, 1), 256, 0, stream>>>(
        ub, 256, 0, wtint, 256, nullptr, nullptr, xz, 1024, 0);
    // 7. depthwise conv + silu -> xbuf fp32 [16384][512]
    k_dwconv<<<(M2*128)/256, 256, 0, stream>>>(xz, wdw, bdw, xbuf);
    // 8. x_proj (fp32) -> dbc [16384][48]
    k_gemm<0><<<dim3(1, M2/64), 256, 0, stream>>>(xbuf, Din, wtx, nullptr, dbc, M2, 48, Din);
    // 9. dt_proj + softplus (fp32) -> dtbuf [16384][512]
    k_gemm<1><<<dim3(8, M2/64), 256, 0, stream>>>(dbc, 48, wtdt, dtb, dtbuf, M2, 512, 16);
    // 10. chunked selective scan -> yf fp32 [16384][512]
    k_scan_a<<<dim3(NCH, Din/16, Bn), 256, 0, stream>>>(dtbuf, xbuf, dbc, alog, hend, Pbuf);
    k_scan_b<<<(Bn*Din*Nst)/256, 256, 0, stream>>>(hend, Pbuf, hin);
    k_scan_c<<<dim3(NCH, Din/16, Bn), 256, 0, stream>>>(dtbuf, xbuf, xz, dbc, alog, Dp, hin, yf);
    // 11. mean over t (out_proj commutes with mean)
    hipMemsetAsync(ym, 0, Bn*Din*sizeof(float), stream);
    k_mean2<<<dim3(8, 2, 16), 256, 0, stream>>>(yf, ym);
    // 12. tail: out_proj on means + fc -> logits
    k_tail<<<8, 256, 0, stream>>>(ym, ow, fcw, fcb, out);
}

// Round 7
// 521.108 us; speedup vs baseline: 2.3150x; 1.2028x over previous
//
#include <hip/hip_runtime.h>
#include <hip/hip_bf16.h>

// ---------------- problem constants ----------------
constexpr int Bn   = 8;
constexpr int L    = 4096;
constexpr int E    = 256;
constexpr int Lh   = 2048;
constexpr int C1n  = 128;
constexpr int Dlat = 256;
constexpr int Din  = 512;
constexpr int Nst  = 16;
constexpr int M2   = Bn * Lh;   // 16384
constexpr int NCH  = 64;        // scan chunks
constexpr int TC   = 32;        // timesteps per chunk

// ---------------- workspace layout (float offsets) ----------------
constexpr long o_wtx   = 0;                         // [512][48] fp32
constexpr long o_wtdt  = o_wtx  + 512L*48;          // [16][512] fp32
constexpr long o_bf    = o_wtdt + 16L*512;          // bf16 weights region (shorts)
constexpr long o_xeb   = o_bf    + 524288/2;        // xe bf16 [8][4100][256] padded
constexpr long o_out1b = o_xeb   + (8L*4100*256)/2; // out1 bf16 [8][2050][128] padded
constexpr long o_ub    = o_out1b + (8L*2050*128)/2; // u bf16 [16384][256]
constexpr long o_xz    = o_ub    + (16384L*256)/2;  // fp32 [16384][1024]
constexpr long o_xbuf  = o_xz    + 16384L*1024;     // fp32 [16384][512]
constexpr long o_dbc   = o_xbuf  + 16384L*512;      // fp32 [16384][48]
constexpr long o_dt    = o_dbc   + 16384L*48;       // fp32 [16384][512]
constexpr long o_hend  = o_dt    + 16384L*512;      // [8][512][64][16]
constexpr long o_P     = o_hend  + 8L*512*NCH*16;
constexpr long o_hin   = o_P     + 8L*512*NCH*16;
constexpr long o_ym    = o_hin   + 8L*512*NCH*16;   // fp32 [8][512]

typedef __attribute__((ext_vector_type(8))) short bf8_t;
typedef __attribute__((ext_vector_type(4))) float f4_t;

__device__ inline short f2bf(float f) {
    unsigned int u = __float_as_uint(f);
    unsigned int r = (u + 0x7FFFu + ((u >> 16) & 1u)) >> 16;
    return (short)r;
}

// ---------------- weight prep: fp32 transposes + bf16 [N][K] transposes ----------------
__global__ void k_prep(const float* __restrict__ w1, const float* __restrict__ w2,
                       const float* __restrict__ win, const float* __restrict__ xw,
                       const float* __restrict__ dtw, float* __restrict__ ws) {
    int idx = blockIdx.x * 256 + threadIdx.x;
    if (idx < 24576) {                        // wtx[k][n] = xw[n][k]  (fp32)
        int n_ = idx % 48; int k = idx / 48;
        ws[o_wtx + idx] = xw[n_*512 + k];
    } else if (idx < 32768) {                 // wtdt[k][n] = dtw[n][k] (fp32)
        int j = idx - 24576;
        int n_ = j & 511; int k = j >> 9;
        ws[o_wtdt + j] = dtw[n_*16 + k];
    } else if (idx < 557056) {                // bf16 region
        int j = idx - 32768;
        short* wsS = (short*)(ws + o_bf);
        if (j < 163840) {                     // wt1t[n][s*256+c] = w1[n][c][s]
            int n_ = j / 1280; int r = j - n_*1280; int s = r >> 8; int c = r & 255;
            wsS[j] = f2bf(w1[(n_*256 + c)*5 + s]);
        } else if (j < 262144) {              // wt2t[n][s*128+c] = w2[n][c][s]
            int jj = j - 163840;
            int n_ = jj / 384; int r = jj - n_*384; int s = r >> 7; int c = r & 127;
            wsS[j] = f2bf(w2[(n_*128 + c)*3 + s]);
        } else {                              // wtint[n][k] = win[n][k]
            int jj = j - 262144;
            int n_ = jj >> 8; int k = jj & 255;
            wsS[j] = f2bf(win[n_*256 + k]);
        }
    }
}

// ---------------- embedding gather -> padded bf16 [8][4100][256] ----------------
__global__ void k_embed(const int* __restrict__ tok, const float* __restrict__ emb,
                        short* __restrict__ xeb) {
    int idx = blockIdx.x * 256 + threadIdx.x;
    int r = idx >> 5;
    int c8 = (idx & 31) << 3;
    int b = r / 4100; int tr = r - b*4100;
    bf8_t v = {0,0,0,0,0,0,0,0};
    if (tr >= 2 && tr < 4098) {
        int t = tok[b*4096 + tr - 2];
        const float* e = emb + (long)t*256 + c8;
        #pragma unroll
        for (int i = 0; i < 8; ++i) v[i] = f2bf(e[i]);
    }
    *(bf8_t*)&xeb[(long)r*256 + c8] = v;
}

// ---------------- zero pad rows of out1b ----------------
__global__ void k_zpad(short* __restrict__ out1b) {
    int i = threadIdx.x;
    for (int j = i; j < 2048; j += 256) {
        int b = j >> 8; int rsel = (j >> 7) & 1; int c = j & 127;
        long row = (long)b*2050 + (rsel ? 2049 : 0);
        out1b[row*128 + c] = 0;
    }
}

// ---------------- MFMA GEMM (conv-as-GEMM + plain) ----------------
template<int SHIFTS, int CPS, int EPI>
__global__ __launch_bounds__(256) void k_mgemm(const short* __restrict__ A, int ars, long batchA,
                                               const short* __restrict__ Bt, int ktot,
                                               const float* __restrict__ bias,
                                               short* __restrict__ outB, float* __restrict__ outF,
                                               int ors, long batchOut) {
    constexpr int KSTEPS = SHIFTS * CPS;
    int l = threadIdx.x & 63, w = threadIdx.x >> 6;
    int m0 = blockIdx.x * 32;
    int n0 = blockIdx.y * 128 + w * 32;
    long zA = (long)blockIdx.z * batchA;
    long zO = (long)blockIdx.z * batchOut;

    const short* ap = A + zA + (long)(m0 + (l & 15)) * ars + ((l >> 4) << 3);
    const short* bp = Bt + (long)(n0 + (l & 15)) * ktot + ((l >> 4) << 3);

    f4_t acc[2][2];
    #pragma unroll
    for (int i = 0; i < 2; ++i)
        #pragma unroll
        for (int j = 0; j < 2; ++j) acc[i][j] = (f4_t){0.f, 0.f, 0.f, 0.f};

    for (int ks = 0; ks < KSTEPS; ++ks) {
        int shift = ks / CPS;
        int c0 = (ks % CPS) * 32;
        const short* a = ap + (long)shift * ars + c0;
        bf8_t a0 = *(const bf8_t*)a;
        bf8_t a1 = *(const bf8_t*)(a + 16 * ars);
        const short* bq = bp + ks * 32;
        bf8_t b0 = *(const bf8_t*)bq;
        bf8_t b1 = *(const bf8_t*)(bq + 16 * ktot);
        acc[0][0] = __builtin_amdgcn_mfma_f32_16x16x32_bf16(a0, b0, acc[0][0], 0, 0, 0);
        acc[0][1] = __builtin_amdgcn_mfma_f32_16x16x32_bf16(a0, b1, acc[0][1], 0, 0, 0);
        acc[1][0] = __builtin_amdgcn_mfma_f32_16x16x32_bf16(a1, b0, acc[1][0], 0, 0, 0);
        acc[1][1] = __builtin_amdgcn_mfma_f32_16x16x32_bf16(a1, b1, acc[1][1], 0, 0, 0);
    }

    #pragma unroll
    for (int mt = 0; mt < 2; ++mt)
        #pragma unroll
        for (int nt = 0; nt < 2; ++nt) {
            f4_t c = acc[mt][nt];
            int col = n0 + nt * 16 + (l & 15);
            int r0 = m0 + mt * 16 + ((l >> 4) << 2);
            if constexpr (EPI == 0) {
                #pragma unroll
                for (int j = 0; j < 4; ++j)
                    outF[zO + (long)(r0 + j) * ors + col] = c[j];
            } else if constexpr (EPI == 1) {
                float bv = bias[col];
                #pragma unroll
                for (int j = 0; j < 4; ++j)
                    outB[zO + (long)(r0 + j) * ors + col] = f2bf(fmaxf(c[j] + bv, 0.f));
            } else {
                float bv = bias[col];
                float p0 = fmaxf(fmaxf(c[0], c[1]) + bv, 0.f);
                float p1 = fmaxf(fmaxf(c[2], c[3]) + bv, 0.f);
                int tp = r0 >> 1;
                outB[zO + (long)(tp + 1) * ors + col] = f2bf(p0);
                outB[zO + (long)(tp + 2) * ors + col] = f2bf(p1);
            }
        }
}

// ---------------- fp32 GEMM (x_proj / dt_proj path, precision-sensitive) ----------------
template<int ACT>   // 0 = none, 1 = softplus
__global__ __launch_bounds__(256) void k_gemm(const float* __restrict__ A, int lda,
                                              const float* __restrict__ WT,
                                              const float* __restrict__ bias,
                                              float* __restrict__ out,
                                              int M, int N, int K) {
    __shared__ float As[16][68];
    __shared__ float Bs[16][64];
    int n0 = blockIdx.x * 64, m0 = blockIdx.y * 64;
    int tid = threadIdx.x;
    int ti = tid >> 4, tj = tid & 15;
    float acc[4][4] = {};
    for (int k0 = 0; k0 < K; k0 += 16) {
        {
            int mm = tid >> 2, kq = tid & 3;
            float4 v = *(const float4*)&A[(long)(m0 + mm)*lda + k0 + kq*4];
            As[kq*4+0][mm] = v.x; As[kq*4+1][mm] = v.y;
            As[kq*4+2][mm] = v.z; As[kq*4+3][mm] = v.w;
        }
        {
            int kk = tid >> 4, n4 = tid & 15;
            float4 v = {0.f,0.f,0.f,0.f};
            if (n0 + n4*4 < N)
                v = *(const float4*)&WT[(long)(k0 + kk)*N + n0 + n4*4];
            *(float4*)&Bs[kk][n4*4] = v;
        }
        __syncthreads();
        #pragma unroll
        for (int kk = 0; kk < 16; ++kk) {
            float4 av = *(float4*)&As[kk][ti*4];
            float4 bv = *(float4*)&Bs[kk][tj*4];
            acc[0][0] += av.x*bv.x; acc[0][1] += av.x*bv.y; acc[0][2] += av.x*bv.z; acc[0][3] += av.x*bv.w;
            acc[1][0] += av.y*bv.x; acc[1][1] += av.y*bv.y; acc[1][2] += av.y*bv.z; acc[1][3] += av.y*bv.w;
            acc[2][0] += av.z*bv.x; acc[2][1] += av.z*bv.y; acc[2][2] += av.z*bv.z; acc[2][3] += av.z*bv.w;
            acc[3][0] += av.w*bv.x; acc[3][1] += av.w*bv.y; acc[3][2] += av.w*bv.z; acc[3][3] += av.w*bv.w;
        }
        __syncthreads();
    }
    if (n0 + tj*4 >= N) return;
    float4 bv = {0.f,0.f,0.f,0.f};
    if (bias) bv = *(const float4*)&bias[n0 + tj*4];
    #pragma unroll
    for (int i = 0; i < 4; ++i) {
        int m = m0 + ti*4 + i;
        float4 v;
        v.x = acc[i][0] + bv.x; v.y = acc[i][1] + bv.y;
        v.z = acc[i][2] + bv.z; v.w = acc[i][3] + bv.w;
        if (ACT == 1) {
            v.x = (v.x > 20.f) ? v.x : log1pf(__expf(v.x));
            v.y = (v.y > 20.f) ? v.y : log1pf(__expf(v.y));
            v.z = (v.z > 20.f) ? v.z : log1pf(__expf(v.z));
            v.w = (v.w > 20.f) ? v.w : log1pf(__expf(v.w));
        }
        *(float4*)&out[(long)m*N + n0 + tj*4] = v;
    }
}

// ---------------- causal depthwise conv (k=4) + SiLU ----------------
__global__ void k_dwconv(const float* __restrict__ xz, const float* __restrict__ wdw,
                         const float* __restrict__ bdw, float* __restrict__ xout) {
    int idx = blockIdx.x * 256 + threadIdx.x;
    int d4 = idx & 127; int rem = idx >> 7;
    int t = rem & 2047; int b = rem >> 11;
    int d0 = d4 * 4;
    float4 acc = *(const float4*)&bdw[d0];
    #pragma unroll
    for (int k = 0; k < 4; ++k) {
        int tt = t - 3 + k;
        if (tt >= 0) {
            float4 v = *(const float4*)&xz[((long)(b*Lh + tt))*1024 + d0];
            acc.x += v.x * wdw[(d0+0)*4 + k];
            acc.y += v.y * wdw[(d0+1)*4 + k];
            acc.z += v.z * wdw[(d0+2)*4 + k];
            acc.w += v.w * wdw[(d0+3)*4 + k];
        }
    }
    acc.x = acc.x / (1.f + __expf(-acc.x));
    acc.y = acc.y / (1.f + __expf(-acc.y));
    acc.z = acc.z / (1.f + __expf(-acc.z));
    acc.w = acc.w / (1.f + __expf(-acc.w));
    *(float4*)&xout[(long)idx * 4] = acc;
}

// ---------------- chunked selective scan, register-state (1 lane = 1 channel) ----------------
// Phase A: local scan (h=0) over TC steps -> hend[.,16], P[.,16]
__global__ __launch_bounds__(256) void k_scan_a(const float* __restrict__ dt,
                                                const float* __restrict__ x,
                                                const float* __restrict__ dbc,
                                                const float* __restrict__ A_log,
                                                float* __restrict__ hend,
                                                float* __restrict__ Pbuf) {
    __shared__ float4 Bs4[TC][4];
    int c = blockIdx.x;               // chunk
    int b = blockIdx.z;
    int tid = threadIdx.x;
    int d = blockIdx.y * 256 + tid;   // channel
    // stage B (wave-uniform) into LDS
    for (int i = tid; i < TC*4; i += 256) {
        int tt = i >> 2, q = i & 3;
        Bs4[tt][q] = *(const float4*)&dbc[((long)b*Lh + c*TC + tt)*48 + 16 + q*4];
    }
    __syncthreads();
    float A_[16];
    #pragma unroll
    for (int n = 0; n < 16; ++n) A_[n] = -__expf(A_log[d*16 + n]);
    float h[16];
    #pragma unroll
    for (int n = 0; n < 16; ++n) h[n] = 0.f;
    float sd = 0.f;
    long base = ((long)b*Lh + c*TC)*512 + d;
    #pragma unroll 4
    for (int tt = 0; tt < TC; ++tt) {
        float dtv = dt[base + (long)tt*512];
        float xv  = x[base + (long)tt*512];
        float u = dtv * xv;
        sd += dtv;
        float Bv[16];
        *(float4*)&Bv[0]  = Bs4[tt][0]; *(float4*)&Bv[4]  = Bs4[tt][1];
        *(float4*)&Bv[8]  = Bs4[tt][2]; *(float4*)&Bv[12] = Bs4[tt][3];
        #pragma unroll
        for (int n = 0; n < 16; ++n) {
            float dA = __expf(dtv * A_[n]);
            h[n] = h[n] * dA + u * Bv[n];
        }
    }
    long o = (((long)b*Din + d)*NCH + c)*16;
    #pragma unroll
    for (int n = 0; n < 16; ++n) hend[o + n] = h[n];
    #pragma unroll
    for (int n = 0; n < 16; ++n) Pbuf[o + n] = __expf(A_[n] * sd);
}

// Phase B: serial combine over chunks -> carry-in hin
__global__ void k_scan_b(const float* __restrict__ hend, const float* __restrict__ Pbuf,
                         float* __restrict__ hin) {
    int idx = blockIdx.x * 256 + threadIdx.x;   // (b,d,n): 65536
    int n = idx & 15; long bd = idx >> 4;
    long base = bd * NCH * 16 + n;
    float h = 0.f;
    for (int c = 0; c < NCH; ++c) {
        hin[base + c*16] = h;
        h = hend[base + c*16] + Pbuf[base + c*16] * h;
    }
}

// Phase C: scan with carry-in; fused y = (p + x*Dp)*silu(z), accumulated over t -> ym
__global__ __launch_bounds__(256) void k_scan_c(const float* __restrict__ dt,
                                                const float* __restrict__ x,
                                                const float* __restrict__ xz,
                                                const float* __restrict__ dbc,
                                                const float* __restrict__ A_log,
                                                const float* __restrict__ Dp,
                                                const float* __restrict__ hin,
                                                float* __restrict__ ym) {
    __shared__ float4 Bs4[TC][4], Cs4[TC][4];
    int c = blockIdx.x;
    int b = blockIdx.z;
    int tid = threadIdx.x;
    int d = blockIdx.y * 256 + tid;
    for (int i = tid; i < TC*4; i += 256) {
        int tt = i >> 2, q = i & 3;
        long rb = ((long)b*Lh + c*TC + tt)*48;
        Bs4[tt][q] = *(const float4*)&dbc[rb + 16 + q*4];
        Cs4[tt][q] = *(const float4*)&dbc[rb + 32 + q*4];
    }
    __syncthreads();
    float A_[16];
    #pragma unroll
    for (int n = 0; n < 16; ++n) A_[n] = -__expf(A_log[d*16 + n]);
    float h[16];
    long o = (((long)b*Din + d)*NCH + c)*16;
    #pragma unroll
    for (int n = 0; n < 16; ++n) h[n] = hin[o + n];
    float Dpv = Dp[d];
    float ysum = 0.f;
    long base = ((long)b*Lh + c*TC)*512 + d;
    long zbase = ((long)b*Lh + c*TC)*1024 + 512 + d;
    #pragma unroll 2
    for (int tt = 0; tt < TC; ++tt) {
        float dtv = dt[base + (long)tt*512];
        float xv  = x[base + (long)tt*512];
        float zv  = xz[zbase + (long)tt*1024];
        float u = dtv * xv;
        float Bv[16], Cv[16];
        *(float4*)&Bv[0]  = Bs4[tt][0]; *(float4*)&Bv[4]  = Bs4[tt][1];
        *(float4*)&Bv[8]  = Bs4[tt][2]; *(float4*)&Bv[12] = Bs4[tt][3];
        *(float4*)&Cv[0]  = Cs4[tt][0]; *(float4*)&Cv[4]  = Cs4[tt][1];
        *(float4*)&Cv[8]  = Cs4[tt][2]; *(float4*)&Cv[12] = Cs4[tt][3];
        float p = 0.f;
        #pragma unroll
        for (int n = 0; n < 16; ++n) {
            float dA = __expf(dtv * A_[n]);
            h[n] = h[n] * dA + u * Bv[n];
            p += h[n] * Cv[n];
        }
        float sz = zv / (1.f + __expf(-zv));
        ysum += (p + xv * Dpv) * sz;
    }
    atomicAdd(&ym[b*Din + d], ysum);
}

// ---------------- tail: xm = (ym/2048) @ ow^T ; logits = xm @ fcw^T + fcb ----------------
__global__ void k_tail(const float* __restrict__ ym, const float* __restrict__ ow,
                       const float* __restrict__ fcw, const float* __restrict__ fcb,
                       float* __restrict__ out) {
    __shared__ float yls[512];
    __shared__ float xs[256];
    int b = blockIdx.x, c = threadIdx.x;
    yls[c] = ym[b*512 + c];
    yls[c + 256] = ym[b*512 + 256 + c];
    __syncthreads();
    float s = 0.f;
    for (int d = 0; d < 512; ++d) s += yls[d] * ow[c*512 + d];
    xs[c] = s * (1.f / 2048.f);
    __syncthreads();
    if (c < 10) {
        float t = fcb[c];
        for (int k = 0; k < 256; ++k) t += xs[k] * fcw[c*256 + k];
        out[b*10 + c] = t;
    }
}

extern "C" void kernel_launch(void* const* d_in, const int* in_sizes, int n_in,
                              void* d_out, int out_size, void* d_ws, size_t ws_size,
                              hipStream_t stream) {
    const int*   tok  = (const int*)d_in[0];
    const float* emb  = (const float*)d_in[1];
    const float* w1   = (const float*)d_in[2];
    const float* b1   = (const float*)d_in[3];
    const float* w2   = (const float*)d_in[4];
    const float* b2   = (const float*)d_in[5];
    const float* win  = (const float*)d_in[6];
    const float* wdw  = (const float*)d_in[7];
    const float* bdw  = (const float*)d_in[8];
    const float* xw   = (const float*)d_in[9];
    const float* dtw  = (const float*)d_in[10];
    const float* dtb  = (const float*)d_in[11];
    const float* alog = (const float*)d_in[12];
    const float* Dp   = (const float*)d_in[13];
    const float* ow   = (const float*)d_in[14];
    const float* fcw  = (const float*)d_in[15];
    const float* fcb  = (const float*)d_in[16];
    float* ws  = (float*)d_ws;
    float* out = (float*)d_out;

    float* wtx   = ws + o_wtx;
    float* wtdt  = ws + o_wtdt;
    short* wt1t  = (short*)(ws + o_bf);
    short* wt2t  = wt1t + 163840;
    short* wtint = wt2t + 98304;
    short* xeb   = (short*)(ws + o_xeb);
    short* out1b = (short*)(ws + o_out1b);
    short* ub    = (short*)(ws + o_ub);
    float* xz    = ws + o_xz;
    float* xbuf  = ws + o_xbuf;
    float* dbc   = ws + o_dbc;
    float* dtbuf = ws + o_dt;
    float* hend  = ws + o_hend;
    float* Pbuf  = ws + o_P;
    float* hin   = ws + o_hin;
    float* ym    = ws + o_ym;

    // 1. weight prep
    k_prep<<<2176, 256, 0, stream>>>(w1, w2, win, xw, dtw, ws);
    // 2. embedding -> padded bf16 xe [8][4100][256]
    k_embed<<<4100, 256, 0, stream>>>(tok, emb, xeb);
    // 3. zero pad rows of out1b; zero ym accumulators
    k_zpad<<<1, 256, 0, stream>>>(out1b);
    hipMemsetAsync(ym, 0, Bn*Din*sizeof(float), stream);
    // 4. conv1 (K=1280) + relu + pool -> out1b bf16 [8][2050][128]
    k_mgemm<5, 8, 2><<<dim3(128, 1, 8), 256, 0, stream>>>(
        xeb, 256, 4100L*256, wt1t, 1280, b1, out1b, nullptr, 128, 2050L*128);
    // 5. conv2 (K=384) + relu -> ub bf16 [16384][256]
    k_mgemm<3, 4, 1><<<dim3(64, 2, 8), 256, 0, stream>>>(
        out1b, 128, 2050L*128, wt2t, 384, b2, ub, nullptr, 256, 2048L*256);
    // 6. in_proj (K=256) -> xz fp32 [16384][1024]
    k_mgemm<1, 8, 0><<<dim3(512, 8, 1), 256, 0, stream>>>(
        ub, 256, 0, wtint, 256, nullptr, nullptr, xz, 1024, 0);
    // 7. depthwise conv + silu -> xbuf fp32 [16384][512]
    k_dwconv<<<(M2*128)/256, 256, 0, stream>>>(xz, wdw, bdw, xbuf);
    // 8. x_proj (fp32) -> dbc [16384][48]
    k_gemm<0><<<dim3(1, M2/64), 256, 0, stream>>>(xbuf, Din, wtx, nullptr, dbc, M2, 48, Din);
    // 9. dt_proj + softplus (fp32) -> dtbuf [16384][512]
    k_gemm<1><<<dim3(8, M2/64), 256, 0, stream>>>(dbc, 48, wtdt, dtb, dtbuf, M2, 512, 16);
    // 10. chunked selective scan (register-state), fused gate+skip+mean -> ym [8][512]
    k_scan_a<<<dim3(NCH, 2, Bn), 256, 0, stream>>>(dtbuf, xbuf, dbc, alog, hend, Pbuf);
    k_scan_b<<<(Bn*Din*Nst)/256, 256, 0, stream>>>(hend, Pbuf, hin);
    k_scan_c<<<dim3(NCH, 2, Bn), 256, 0, stream>>>(dtbuf, xbuf, xz, dbc, alog, Dp, hin, ym);
    // 11. tail: out_proj on means + fc -> logits
    k_tail<<<8, 256, 0, stream>>>(ym, ow, fcw, fcb, out);
}

// Round 9
// 413.526 us; speedup vs baseline: 2.9173x; 1.2602x over previous
//
#include <hip/hip_runtime.h>
#include <hip/hip_bf16.h>

// ---------------- problem constants ----------------
constexpr int Bn   = 8;
constexpr int L    = 4096;
constexpr int E    = 256;
constexpr int Lh   = 2048;
constexpr int C1n  = 128;
constexpr int Dlat = 256;
constexpr int Din  = 512;
constexpr int Nst  = 16;
constexpr int M2   = Bn * Lh;   // 16384
constexpr int NCH  = 64;        // scan chunks
constexpr int TC   = 32;        // timesteps per chunk

// ---------------- workspace layout (float offsets) ----------------
constexpr long o_wtx   = 0;                         // [512][48] fp32
constexpr long o_wtdt  = o_wtx  + 512L*48;          // [16][512] fp32
constexpr long o_bf    = o_wtdt + 16L*512;          // bf16 weights region (shorts)
constexpr long o_xeb   = o_bf    + 524288/2;        // xe bf16 [8][4100][256] padded
constexpr long o_out1b = o_xeb   + (8L*4100*256)/2; // out1 bf16 [8][2050][128] padded
constexpr long o_ub    = o_out1b + (8L*2050*128)/2; // u bf16 [16384][256]
constexpr long o_xz    = o_ub    + (16384L*256)/2;  // fp32 [16384][1024]
constexpr long o_xbuf  = o_xz    + 16384L*1024;     // fp32 [16384][512]
constexpr long o_dbc   = o_xbuf  + 16384L*512;      // fp32 [16384][48]
constexpr long o_dt    = o_dbc   + 16384L*48;       // fp32 [16384][512]
constexpr long o_hend  = o_dt    + 16384L*512;      // [8][512][64][16]
constexpr long o_P     = o_hend  + 8L*512*NCH*16;
constexpr long o_hin   = o_P     + 8L*512*NCH*16;
constexpr long o_ym    = o_hin   + 8L*512*NCH*16;   // fp32 [8][512]

typedef __attribute__((ext_vector_type(8))) short bf8_t;
typedef __attribute__((ext_vector_type(4))) float f4_t;

__device__ inline short f2bf(float f) {
    unsigned int u = __float_as_uint(f);
    unsigned int r = (u + 0x7FFFu + ((u >> 16) & 1u)) >> 16;
    return (short)r;
}

// ---------------- weight prep: fp32 transposes + bf16 [N][K] transposes ----------------
__global__ void k_prep(const float* __restrict__ w1, const float* __restrict__ w2,
                       const float* __restrict__ win, const float* __restrict__ xw,
                       const float* __restrict__ dtw, float* __restrict__ ws) {
    int idx = blockIdx.x * 256 + threadIdx.x;
    if (idx < 24576) {                        // wtx[k][n] = xw[n][k]  (fp32)
        int n_ = idx % 48; int k = idx / 48;
        ws[o_wtx + idx] = xw[n_*512 + k];
    } else if (idx < 32768) {                 // wtdt[k][n] = dtw[n][k] (fp32)
        int j = idx - 24576;
        int n_ = j & 511; int k = j >> 9;
        ws[o_wtdt + j] = dtw[n_*16 + k];
    } else if (idx < 557056) {                // bf16 region
        int j = idx - 32768;
        short* wsS = (short*)(ws + o_bf);
        if (j < 163840) {                     // wt1t[n][s*256+c] = w1[n][c][s]
            int n_ = j / 1280; int r = j - n_*1280; int s = r >> 8; int c = r & 255;
            wsS[j] = f2bf(w1[(n_*256 + c)*5 + s]);
        } else if (j < 262144) {              // wt2t[n][s*128+c] = w2[n][c][s]
            int jj = j - 163840;
            int n_ = jj / 384; int r = jj - n_*384; int s = r >> 7; int c = r & 127;
            wsS[j] = f2bf(w2[(n_*128 + c)*3 + s]);
        } else {                              // wtint[n][k] = win[n][k]
            int jj = j - 262144;
            int n_ = jj >> 8; int k = jj & 255;
            wsS[j] = f2bf(win[n_*256 + k]);
        }
    }
}

// ---------------- embedding gather -> padded bf16 [8][4100][256] ----------------
__global__ void k_embed(const int* __restrict__ tok, const float* __restrict__ emb,
                        short* __restrict__ xeb) {
    int idx = blockIdx.x * 256 + threadIdx.x;
    int r = idx >> 5;
    int c8 = (idx & 31) << 3;
    int b = r / 4100; int tr = r - b*4100;
    bf8_t v = {0,0,0,0,0,0,0,0};
    if (tr >= 2 && tr < 4098) {
        int t = tok[b*4096 + tr - 2];
        const float* e = emb + (long)t*256 + c8;
        #pragma unroll
        for (int i = 0; i < 8; ++i) v[i] = f2bf(e[i]);
    }
    *(bf8_t*)&xeb[(long)r*256 + c8] = v;
}

// ---------------- zero pad rows of out1b ----------------
__global__ void k_zpad(short* __restrict__ out1b) {
    int i = threadIdx.x;
    for (int j = i; j < 2048; j += 256) {
        int b = j >> 8; int rsel = (j >> 7) & 1; int c = j & 127;
        long row = (long)b*2050 + (rsel ? 2049 : 0);
        out1b[row*128 + c] = 0;
    }
}

// ---------------- LDS-staged double-buffered MFMA GEMM ----------------
// Block tile 64x128, BK=64, 4 waves: wave w owns cols w*32..w*32+31 (4x2 frags).
// K-tile kt -> (shift s = kt/TPS, channel offset c0 = (kt%TPS)*64); C = TPS*64.
// EPI: 0 = fp32 store; 1 = bias+relu -> bf16; 2 = bias+relu+maxpool2 -> bf16 (padded out)
template<int SHIFTS, int TPS, int EPI>
__global__ __launch_bounds__(256) void k_mgemm(const short* __restrict__ A, int ars, long batchA,
                                               const short* __restrict__ Bt, int ktot,
                                               const float* __restrict__ bias,
                                               short* __restrict__ outB, float* __restrict__ outF,
                                               int ors, long batchOut) {
    constexpr int KT = SHIFTS * TPS;
    constexpr int C  = TPS * 64;
    __shared__ short As[2][64][68];
    __shared__ short Bs[2][128][68];
    int tid = threadIdx.x;
    int l = tid & 63, w = tid >> 6;
    int m0 = blockIdx.x * 64;
    int n0 = blockIdx.y * 128;
    long zA = (long)blockIdx.z * batchA;
    long zO = (long)blockIdx.z * batchOut;

    bf8_t aReg[2], bReg[4];

    auto gload = [&](int kt) {
        int s = kt / TPS, c0 = (kt % TPS) * 64;
        const short* Ab = A + zA + (long)(m0 + s) * ars + c0;
        #pragma unroll
        for (int j = 0; j < 2; ++j) {
            int idx = tid + j*256;
            int r = idx >> 3, cc = (idx & 7) * 8;
            aReg[j] = *(const bf8_t*)&Ab[(long)r * ars + cc];
        }
        const short* Bb = Bt + (long)n0 * ktot + s * C + c0;
        #pragma unroll
        for (int j = 0; j < 4; ++j) {
            int idx = tid + j*256;
            int r = idx >> 3, cc = (idx & 7) * 8;
            bReg[j] = *(const bf8_t*)&Bb[(long)r * ktot + cc];
        }
    };
    auto lwrite = [&](int buf) {
        #pragma unroll
        for (int j = 0; j < 2; ++j) {
            int idx = tid + j*256;
            int r = idx >> 3, cc = (idx & 7) * 8;
            *(bf8_t*)&As[buf][r][cc] = aReg[j];
        }
        #pragma unroll
        for (int j = 0; j < 4; ++j) {
            int idx = tid + j*256;
            int r = idx >> 3, cc = (idx & 7) * 8;
            *(bf8_t*)&Bs[buf][r][cc] = bReg[j];
        }
    };

    f4_t acc[4][2];
    #pragma unroll
    for (int m = 0; m < 4; ++m)
        #pragma unroll
        for (int n = 0; n < 2; ++n) acc[m][n] = (f4_t){0.f, 0.f, 0.f, 0.f};

    gload(0);
    lwrite(0);
    __syncthreads();
    for (int kt = 0; kt < KT; ++kt) {
        int buf = kt & 1;
        if (kt + 1 < KT) gload(kt + 1);      // issue next-tile loads early (hide under MFMA)
        #pragma unroll
        for (int ks = 0; ks < 2; ++ks) {
            int kk = ks*32 + ((l >> 4) << 3);
            bf8_t a[4], b[2];
            #pragma unroll
            for (int m = 0; m < 4; ++m)
                a[m] = *(const bf8_t*)&As[buf][m*16 + (l & 15)][kk];
            #pragma unroll
            for (int n = 0; n < 2; ++n)
                b[n] = *(const bf8_t*)&Bs[buf][w*32 + n*16 + (l & 15)][kk];
            #pragma unroll
            for (int m = 0; m < 4; ++m)
                #pragma unroll
                for (int n = 0; n < 2; ++n)
                    acc[m][n] = __builtin_amdgcn_mfma_f32_16x16x32_bf16(a[m], b[n], acc[m][n], 0, 0, 0);
        }
        if (kt + 1 < KT) {
            lwrite(buf ^ 1);                 // write other buffer (prev reads of it fenced by last barrier)
            __syncthreads();
        }
    }

    #pragma unroll
    for (int mt = 0; mt < 4; ++mt)
        #pragma unroll
        for (int nt = 0; nt < 2; ++nt) {
            f4_t c = acc[mt][nt];
            int col = n0 + w*32 + nt*16 + (l & 15);
            int r0 = m0 + mt*16 + ((l >> 4) << 2);
            if constexpr (EPI == 0) {
                #pragma unroll
                for (int j = 0; j < 4; ++j)
                    outF[zO + (long)(r0 + j) * ors + col] = c[j];
            } else if constexpr (EPI == 1) {
                float bv = bias[col];
                #pragma unroll
                for (int j = 0; j < 4; ++j)
                    outB[zO + (long)(r0 + j) * ors + col] = f2bf(fmaxf(c[j] + bv, 0.f));
            } else {
                float bv = bias[col];
                float p0 = fmaxf(fmaxf(c[0], c[1]) + bv, 0.f);
                float p1 = fmaxf(fmaxf(c[2], c[3]) + bv, 0.f);
                int tp = r0 >> 1;
                outB[zO + (long)(tp + 1) * ors + col] = f2bf(p0);
                outB[zO + (long)(tp + 2) * ors + col] = f2bf(p1);
            }
        }
}

// ---------------- fp32 GEMM (x_proj / dt_proj path, precision-sensitive) ----------------
template<int ACT>   // 0 = none, 1 = softplus
__global__ __launch_bounds__(256) void k_gemm(const float* __restrict__ A, int lda,
                                              const float* __restrict__ WT,
                                              const float* __restrict__ bias,
                                              float* __restrict__ out,
                                              int M, int N, int K) {
    __shared__ float As[16][68];
    __shared__ float Bs[16][64];
    int n0 = blockIdx.x * 64, m0 = blockIdx.y * 64;
    int tid = threadIdx.x;
    int ti = tid >> 4, tj = tid & 15;
    float acc[4][4] = {};
    for (int k0 = 0; k0 < K; k0 += 16) {
        {
            int mm = tid >> 2, kq = tid & 3;
            float4 v = *(const float4*)&A[(long)(m0 + mm)*lda + k0 + kq*4];
            As[kq*4+0][mm] = v.x; As[kq*4+1][mm] = v.y;
            As[kq*4+2][mm] = v.z; As[kq*4+3][mm] = v.w;
        }
        {
            int kk = tid >> 4, n4 = tid & 15;
            float4 v = {0.f,0.f,0.f,0.f};
            if (n0 + n4*4 < N)
                v = *(const float4*)&WT[(long)(k0 + kk)*N + n0 + n4*4];
            *(float4*)&Bs[kk][n4*4] = v;
        }
        __syncthreads();
        #pragma unroll
        for (int kk = 0; kk < 16; ++kk) {
            float4 av = *(float4*)&As[kk][ti*4];
            float4 bv = *(float4*)&Bs[kk][tj*4];
            acc[0][0] += av.x*bv.x; acc[0][1] += av.x*bv.y; acc[0][2] += av.x*bv.z; acc[0][3] += av.x*bv.w;
            acc[1][0] += av.y*bv.x; acc[1][1] += av.y*bv.y; acc[1][2] += av.y*bv.z; acc[1][3] += av.y*bv.w;
            acc[2][0] += av.z*bv.x; acc[2][1] += av.z*bv.y; acc[2][2] += av.z*bv.z; acc[2][3] += av.z*bv.w;
            acc[3][0] += av.w*bv.x; acc[3][1] += av.w*bv.y; acc[3][2] += av.w*bv.z; acc[3][3] += av.w*bv.w;
        }
        __syncthreads();
    }
    if (n0 + tj*4 >= N) return;
    float4 bv = {0.f,0.f,0.f,0.f};
    if (bias) bv = *(const float4*)&bias[n0 + tj*4];
    #pragma unroll
    for (int i = 0; i < 4; ++i) {
        int m = m0 + ti*4 + i;
        float4 v;
        v.x = acc[i][0] + bv.x; v.y = acc[i][1] + bv.y;
        v.z = acc[i][2] + bv.z; v.w = acc[i][3] + bv.w;
        if (ACT == 1) {
            v.x = (v.x > 20.f) ? v.x : log1pf(__expf(v.x));
            v.y = (v.y > 20.f) ? v.y : log1pf(__expf(v.y));
            v.z = (v.z > 20.f) ? v.z : log1pf(__expf(v.z));
            v.w = (v.w > 20.f) ? v.w : log1pf(__expf(v.w));
        }
        *(float4*)&out[(long)m*N + n0 + tj*4] = v;
    }
}

// ---------------- causal depthwise conv (k=4) + SiLU ----------------
__global__ void k_dwconv(const float* __restrict__ xz, const float* __restrict__ wdw,
                         const float* __restrict__ bdw, float* __restrict__ xout) {
    int idx = blockIdx.x * 256 + threadIdx.x;
    int d4 = idx & 127; int rem = idx >> 7;
    int t = rem & 2047; int b = rem >> 11;
    int d0 = d4 * 4;
    float4 acc = *(const float4*)&bdw[d0];
    #pragma unroll
    for (int k = 0; k < 4; ++k) {
        int tt = t - 3 + k;
        if (tt >= 0) {
            float4 v = *(const float4*)&xz[((long)(b*Lh + tt))*1024 + d0];
            acc.x += v.x * wdw[(d0+0)*4 + k];
            acc.y += v.y * wdw[(d0+1)*4 + k];
            acc.z += v.z * wdw[(d0+2)*4 + k];
            acc.w += v.w * wdw[(d0+3)*4 + k];
        }
    }
    acc.x = acc.x / (1.f + __expf(-acc.x));
    acc.y = acc.y / (1.f + __expf(-acc.y));
    acc.z = acc.z / (1.f + __expf(-acc.z));
    acc.w = acc.w / (1.f + __expf(-acc.w));
    *(float4*)&xout[(long)idx * 4] = acc;
}

// ---------------- chunked selective scan, register-state (1 lane = 1 channel) ----------------
__global__ __launch_bounds__(256) void k_scan_a(const float* __restrict__ dt,
                                                const float* __restrict__ x,
                                                const float* __restrict__ dbc,
                                                const float* __restrict__ A_log,
                                                float* __restrict__ hend,
                                                float* __restrict__ Pbuf) {
    __shared__ float4 Bs4[TC][4];
    int c = blockIdx.x;
    int b = blockIdx.z;
    int tid = threadIdx.x;
    int d = blockIdx.y * 256 + tid;
    for (int i = tid; i < TC*4; i += 256) {
        int tt = i >> 2, q = i & 3;
        Bs4[tt][q] = *(const float4*)&dbc[((long)b*Lh + c*TC + tt)*48 + 16 + q*4];
    }
    __syncthreads();
    float A_[16];
    #pragma unroll
    for (int n = 0; n < 16; ++n) A_[n] = -__expf(A_log[d*16 + n]);
    float h[16];
    #pragma unroll
    for (int n = 0; n < 16; ++n) h[n] = 0.f;
    float sd = 0.f;
    long base = ((long)b*Lh + c*TC)*512 + d;
    #pragma unroll 4
    for (int tt = 0; tt < TC; ++tt) {
        float dtv = dt[base + (long)tt*512];
        float xv  = x[base + (long)tt*512];
        float u = dtv * xv;
        sd += dtv;
        float Bv[16];
        *(float4*)&Bv[0]  = Bs4[tt][0]; *(float4*)&Bv[4]  = Bs4[tt][1];
        *(float4*)&Bv[8]  = Bs4[tt][2]; *(float4*)&Bv[12] = Bs4[tt][3];
        #pragma unroll
        for (int n = 0; n < 16; ++n) {
            float dA = __expf(dtv * A_[n]);
            h[n] = h[n] * dA + u * Bv[n];
        }
    }
    long o = (((long)b*Din + d)*NCH + c)*16;
    #pragma unroll
    for (int n = 0; n < 16; ++n) hend[o + n] = h[n];
    #pragma unroll
    for (int n = 0; n < 16; ++n) Pbuf[o + n] = __expf(A_[n] * sd);
}

__global__ void k_scan_b(const float* __restrict__ hend, const float* __restrict__ Pbuf,
                         float* __restrict__ hin) {
    int idx = blockIdx.x * 256 + threadIdx.x;
    int n = idx & 15; long bd = idx >> 4;
    long base = bd * NCH * 16 + n;
    float h = 0.f;
    for (int c = 0; c < NCH; ++c) {
        hin[base + c*16] = h;
        h = hend[base + c*16] + Pbuf[base + c*16] * h;
    }
}

__global__ __launch_bounds__(256) void k_scan_c(const float* __restrict__ dt,
                                                const float* __restrict__ x,
                                                const float* __restrict__ xz,
                                                const float* __restrict__ dbc,
                                                const float* __restrict__ A_log,
                                                const float* __restrict__ Dp,
                                                const float* __restrict__ hin,
                                                float* __restrict__ ym) {
    __shared__ float4 Bs4[TC][4], Cs4[TC][4];
    int c = blockIdx.x;
    int b = blockIdx.z;
    int tid = threadIdx.x;
    int d = blockIdx.y * 256 + tid;
    for (int i = tid; i < TC*4; i += 256) {
        int tt = i >> 2, q = i & 3;
        long rb = ((long)b*Lh + c*TC + tt)*48;
        Bs4[tt][q] = *(const float4*)&dbc[rb + 16 + q*4];
        Cs4[tt][q] = *(const float4*)&dbc[rb + 32 + q*4];
    }
    __syncthreads();
    float A_[16];
    #pragma unroll
    for (int n = 0; n < 16; ++n) A_[n] = -__expf(A_log[d*16 + n]);
    float h[16];
    long o = (((long)b*Din + d)*NCH + c)*16;
    #pragma unroll
    for (int n = 0; n < 16; ++n) h[n] = hin[o + n];
    float Dpv = Dp[d];
    float ysum = 0.f;
    long base = ((long)b*Lh + c*TC)*512 + d;
    long zbase = ((long)b*Lh + c*TC)*1024 + 512 + d;
    #pragma unroll 2
    for (int tt = 0; tt < TC; ++tt) {
        float dtv = dt[base + (long)tt*512];
        float xv  = x[base + (long)tt*512];
        float zv  = xz[zbase + (long)tt*1024];
        float u = dtv * xv;
        float Bv[16], Cv[16];
        *(float4*)&Bv[0]  = Bs4[tt][0]; *(float4*)&Bv[4]  = Bs4[tt][1];
        *(float4*)&Bv[8]  = Bs4[tt][2]; *(float4*)&Bv[12] = Bs4[tt][3];
        *(float4*)&Cv[0]  = Cs4[tt][0]; *(float4*)&Cv[4]  = Cs4[tt][1];
        *(float4*)&Cv[8]  = Cs4[tt][2]; *(float4*)&Cv[12] = Cs4[tt][3];
        float p = 0.f;
        #pragma unroll
        for (int n = 0; n < 16; ++n) {
            float dA = __expf(dtv * A_[n]);
            h[n] = h[n] * dA + u * Bv[n];
            p += h[n] * Cv[n];
        }
        float sz = zv / (1.f + __expf(-zv));
        ysum += (p + xv * Dpv) * sz;
    }
    atomicAdd(&ym[b*Din + d], ysum);
}

// ---------------- tail: xm = (ym/2048) @ ow^T ; logits = xm @ fcw^T + fcb ----------------
__global__ void k_tail(const float* __restrict__ ym, const float* __restrict__ ow,
                       const float* __restrict__ fcw, const float* __restrict__ fcb,
                       float* __restrict__ out) {
    __shared__ float yls[512];
    __shared__ float xs[256];
    int b = blockIdx.x, c = threadIdx.x;
    yls[c] = ym[b*512 + c];
    yls[c + 256] = ym[b*512 + 256 + c];
    __syncthreads();
    float s = 0.f;
    for (int d = 0; d < 512; ++d) s += yls[d] * ow[c*512 + d];
    xs[c] = s * (1.f / 2048.f);
    __syncthreads();
    if (c < 10) {
        float t = fcb[c];
        for (int k = 0; k < 256; ++k) t += xs[k] * fcw[c*256 + k];
        out[b*10 + c] = t;
    }
}

extern "C" void kernel_launch(void* const* d_in, const int* in_sizes, int n_in,
                              void* d_out, int out_size, void* d_ws, size_t ws_size,
                              hipStream_t stream) {
    const int*   tok  = (const int*)d_in[0];
    const float* emb  = (const float*)d_in[1];
    const float* w1   = (const float*)d_in[2];
    const float* b1   = (const float*)d_in[3];
    const float* w2   = (const float*)d_in[4];
    const float* b2   = (const float*)d_in[5];
    const float* win  = (const float*)d_in[6];
    const float* wdw  = (const float*)d_in[7];
    const float* bdw  = (const float*)d_in[8];
    const float* xw   = (const float*)d_in[9];
    const float* dtw  = (const float*)d_in[10];
    const float* dtb  = (const float*)d_in[11];
    const float* alog = (const float*)d_in[12];
    const float* Dp   = (const float*)d_in[13];
    const float* ow   = (const float*)d_in[14];
    const float* fcw  = (const float*)d_in[15];
    const float* fcb  = (const float*)d_in[16];
    float* ws  = (float*)d_ws;
    float* out = (float*)d_out;

    float* wtx   = ws + o_wtx;
    float* wtdt  = ws + o_wtdt;
    short* wt1t  = (short*)(ws + o_bf);
    short* wt2t  = wt1t + 163840;
    short* wtint = wt2t + 98304;
    short* xeb   = (short*)(ws + o_xeb);
    short* out1b = (short*)(ws + o_out1b);
    short* ub    = (short*)(ws + o_ub);
    float* xz    = ws + o_xz;
    float* xbuf  = ws + o_xbuf;
    float* dbc   = ws + o_dbc;
    float* dtbuf = ws + o_dt;
    float* hend  = ws + o_hend;
    float* Pbuf  = ws + o_P;
    float* hin   = ws + o_hin;
    float* ym    = ws + o_ym;

    // 1. weight prep
    k_prep<<<2176, 256, 0, stream>>>(w1, w2, win, xw, dtw, ws);
    // 2. embedding -> padded bf16 xe [8][4100][256]
    k_embed<<<4100, 256, 0, stream>>>(tok, emb, xeb);
    // 3. zero pad rows of out1b; zero ym accumulators
    k_zpad<<<1, 256, 0, stream>>>(out1b);
    hipMemsetAsync(ym, 0, Bn*Din*sizeof(float), stream);
    // 4. conv1 (K=1280, C=256) + relu + pool -> out1b bf16 [8][2050][128]
    k_mgemm<5, 4, 2><<<dim3(64, 1, 8), 256, 0, stream>>>(
        xeb, 256, 4100L*256, wt1t, 1280, b1, out1b, nullptr, 128, 2050L*128);
    // 5. conv2 (K=384, C=128) + relu -> ub bf16 [16384][256]
    k_mgemm<3, 2, 1><<<dim3(32, 2, 8), 256, 0, stream>>>(
        out1b, 128, 2050L*128, wt2t, 384, b2, ub, nullptr, 256, 2048L*256);
    // 6. in_proj (K=256) -> xz fp32 [16384][1024]
    k_mgemm<1, 4, 0><<<dim3(256, 8, 1), 256, 0, stream>>>(
        ub, 256, 0, wtint, 256, nullptr, nullptr, xz, 1024, 0);
    // 7. depthwise conv + silu -> xbuf fp32 [16384][512]
    k_dwconv<<<(M2*128)/256, 256, 0, stream>>>(xz, wdw, bdw, xbuf);
    // 8. x_proj (fp32) -> dbc [16384][48]
    k_gemm<0><<<dim3(1, M2/64), 256, 0, stream>>>(xbuf, Din, wtx, nullptr, dbc, M2, 48, Din);
    // 9. dt_proj + softplus (fp32) -> dtbuf [16384][512]
    k_gemm<1><<<dim3(8, M2/64), 256, 0, stream>>>(dbc, 48, wtdt, dtb, dtbuf, M2, 512, 16);
    // 10. chunked selective scan (register-state), fused gate+skip+mean -> ym [8][512]
    k_scan_a<<<dim3(NCH, 2, Bn), 256, 0, stream>>>(dtbuf, xbuf, dbc, alog, hend, Pbuf);
    k_scan_b<<<(Bn*Din*Nst)/256, 256, 0, stream>>>(hend, Pbuf, hin);
    k_scan_c<<<dim3(NCH, 2, Bn), 256, 0, stream>>>(dtbuf, xbuf, xz, dbc, alog, Dp, hin, ym);
    // 11. tail: out_proj on means + fc -> logits
    k_tail<<<8, 256, 0, stream>>>(ym, ow, fcw, fcb, out);
}

// Round 11
// 353.910 us; speedup vs baseline: 3.4087x; 1.1685x over previous
//
#include <hip/hip_runtime.h>
#include <hip/hip_bf16.h>

// ---------------- problem constants ----------------
constexpr int Bn   = 8;
constexpr int L    = 4096;
constexpr int E    = 256;
constexpr int Lh   = 2048;
constexpr int C1n  = 128;
constexpr int Dlat = 256;
constexpr int Din  = 512;
constexpr int Nst  = 16;
constexpr int M2   = Bn * Lh;   // 16384
constexpr int NCH  = 64;        // scan chunks
constexpr int TC   = 32;        // timesteps per chunk

// ---------------- workspace layout (float offsets) ----------------
constexpr long o_wtx   = 0;                         // [512][48] fp32
constexpr long o_wtdt  = o_wtx  + 512L*48;          // [16][512] fp32
constexpr long o_bf    = o_wtdt + 16L*512;          // bf16 weights region (shorts)
constexpr long o_xeb   = o_bf    + 524288/2;        // xe bf16 [8][4100][256] padded
constexpr long o_out1b = o_xeb   + (8L*4100*256)/2; // out1 bf16 [8][2050][128] padded
constexpr long o_ub    = o_out1b + (8L*2050*128)/2; // u bf16 [16384][256]
constexpr long o_xz    = o_ub    + (16384L*256)/2;  // fp32 [16384][1024]
constexpr long o_xbuf  = o_xz    + 16384L*1024;     // fp32 [16384][512]
constexpr long o_dbc   = o_xbuf  + 16384L*512;      // fp32 [16384][48]
constexpr long o_dt    = o_dbc   + 16384L*48;       // fp32 [16384][512]
constexpr long o_hend  = o_dt    + 16384L*512;      // [8][512][64][16]
constexpr long o_P     = o_hend  + 8L*512*NCH*16;
constexpr long o_hin   = o_P     + 8L*512*NCH*16;
constexpr long o_ym    = o_hin   + 8L*512*NCH*16;   // fp32 [8][512]
constexpr long o_S     = o_ym    + 8L*512;          // [8][512][64][16]
constexpr long o_yp    = o_S     + 8L*512*NCH*16;   // [8][512][64]

typedef __attribute__((ext_vector_type(8))) short bf8_t;
typedef __attribute__((ext_vector_type(4))) float f4_t;

__device__ inline short f2bf(float f) {
    unsigned int u = __float_as_uint(f);
    unsigned int r = (u + 0x7FFFu + ((u >> 16) & 1u)) >> 16;
    return (short)r;
}

// ---------------- weight prep: fp32 transposes + bf16 [N][K] transposes ----------------
__global__ void k_prep(const float* __restrict__ w1, const float* __restrict__ w2,
                       const float* __restrict__ win, const float* __restrict__ xw,
                       const float* __restrict__ dtw, float* __restrict__ ws) {
    int idx = blockIdx.x * 256 + threadIdx.x;
    if (idx < 24576) {                        // wtx[k][n] = xw[n][k]  (fp32)
        int n_ = idx % 48; int k = idx / 48;
        ws[o_wtx + idx] = xw[n_*512 + k];
    } else if (idx < 32768) {                 // wtdt[k][n] = dtw[n][k] (fp32)
        int j = idx - 24576;
        int n_ = j & 511; int k = j >> 9;
        ws[o_wtdt + j] = dtw[n_*16 + k];
    } else if (idx < 557056) {                // bf16 region
        int j = idx - 32768;
        short* wsS = (short*)(ws + o_bf);
        if (j < 163840) {                     // wt1t[n][s*256+c] = w1[n][c][s]
            int n_ = j / 1280; int r = j - n_*1280; int s = r >> 8; int c = r & 255;
            wsS[j] = f2bf(w1[(n_*256 + c)*5 + s]);
        } else if (j < 262144) {              // wt2t[n][s*128+c] = w2[n][c][s]
            int jj = j - 163840;
            int n_ = jj / 384; int r = jj - n_*384; int s = r >> 7; int c = r & 127;
            wsS[j] = f2bf(w2[(n_*128 + c)*3 + s]);
        } else {                              // wtint[n][k] = win[n][k]
            int jj = j - 262144;
            int n_ = jj >> 8; int k = jj & 255;
            wsS[j] = f2bf(win[n_*256 + k]);
        }
    }
}

// ---------------- embedding gather -> padded bf16 [8][4100][256] ----------------
__global__ void k_embed(const int* __restrict__ tok, const float* __restrict__ emb,
                        short* __restrict__ xeb) {
    int idx = blockIdx.x * 256 + threadIdx.x;
    int r = idx >> 5;
    int c8 = (idx & 31) << 3;
    int b = r / 4100; int tr = r - b*4100;
    bf8_t v = {0,0,0,0,0,0,0,0};
    if (tr >= 2 && tr < 4098) {
        int t = tok[b*4096 + tr - 2];
        const float* e = emb + (long)t*256 + c8;
        #pragma unroll
        for (int i = 0; i < 8; ++i) v[i] = f2bf(e[i]);
    }
    *(bf8_t*)&xeb[(long)r*256 + c8] = v;
}

// ---------------- zero pad rows of out1b ----------------
__global__ void k_zpad(short* __restrict__ out1b) {
    int i = threadIdx.x;
    for (int j = i; j < 2048; j += 256) {
        int b = j >> 8; int rsel = (j >> 7) & 1; int c = j & 127;
        long row = (long)b*2050 + (rsel ? 2049 : 0);
        out1b[row*128 + c] = 0;
    }
}

// ---------------- LDS-staged double-buffered MFMA GEMM ----------------
template<int SHIFTS, int TPS, int EPI>
__global__ __launch_bounds__(256) void k_mgemm(const short* __restrict__ A, int ars, long batchA,
                                               const short* __restrict__ Bt, int ktot,
                                               const float* __restrict__ bias,
                                               short* __restrict__ outB, float* __restrict__ outF,
                                               int ors, long batchOut) {
    constexpr int KT = SHIFTS * TPS;
    constexpr int C  = TPS * 64;
    __shared__ short As[2][64][68];
    __shared__ short Bs[2][128][68];
    int tid = threadIdx.x;
    int l = tid & 63, w = tid >> 6;
    int m0 = blockIdx.x * 64;
    int n0 = blockIdx.y * 128;
    long zA = (long)blockIdx.z * batchA;
    long zO = (long)blockIdx.z * batchOut;

    bf8_t aReg[2], bReg[4];

    auto gload = [&](int kt) {
        int s = kt / TPS, c0 = (kt % TPS) * 64;
        const short* Ab = A + zA + (long)(m0 + s) * ars + c0;
        #pragma unroll
        for (int j = 0; j < 2; ++j) {
            int idx = tid + j*256;
            int r = idx >> 3, cc = (idx & 7) * 8;
            aReg[j] = *(const bf8_t*)&Ab[(long)r * ars + cc];
        }
        const short* Bb = Bt + (long)n0 * ktot + s * C + c0;
        #pragma unroll
        for (int j = 0; j < 4; ++j) {
            int idx = tid + j*256;
            int r = idx >> 3, cc = (idx & 7) * 8;
            bReg[j] = *(const bf8_t*)&Bb[(long)r * ktot + cc];
        }
    };
    auto lwrite = [&](int buf) {
        #pragma unroll
        for (int j = 0; j < 2; ++j) {
            int idx = tid + j*256;
            int r = idx >> 3, cc = (idx & 7) * 8;
            *(bf8_t*)&As[buf][r][cc] = aReg[j];
        }
        #pragma unroll
        for (int j = 0; j < 4; ++j) {
            int idx = tid + j*256;
            int r = idx >> 3, cc = (idx & 7) * 8;
            *(bf8_t*)&Bs[buf][r][cc] = bReg[j];
        }
    };

    f4_t acc[4][2];
    #pragma unroll
    for (int m = 0; m < 4; ++m)
        #pragma unroll
        for (int n = 0; n < 2; ++n) acc[m][n] = (f4_t){0.f, 0.f, 0.f, 0.f};

    gload(0);
    lwrite(0);
    __syncthreads();
    for (int kt = 0; kt < KT; ++kt) {
        int buf = kt & 1;
        if (kt + 1 < KT) gload(kt + 1);
        #pragma unroll
        for (int ks = 0; ks < 2; ++ks) {
            int kk = ks*32 + ((l >> 4) << 3);
            bf8_t a[4], b[2];
            #pragma unroll
            for (int m = 0; m < 4; ++m)
                a[m] = *(const bf8_t*)&As[buf][m*16 + (l & 15)][kk];
            #pragma unroll
            for (int n = 0; n < 2; ++n)
                b[n] = *(const bf8_t*)&Bs[buf][w*32 + n*16 + (l & 15)][kk];
            #pragma unroll
            for (int m = 0; m < 4; ++m)
                #pragma unroll
                for (int n = 0; n < 2; ++n)
                    acc[m][n] = __builtin_amdgcn_mfma_f32_16x16x32_bf16(a[m], b[n], acc[m][n], 0, 0, 0);
        }
        if (kt + 1 < KT) {
            lwrite(buf ^ 1);
            __syncthreads();
        }
    }

    #pragma unroll
    for (int mt = 0; mt < 4; ++mt)
        #pragma unroll
        for (int nt = 0; nt < 2; ++nt) {
            f4_t c = acc[mt][nt];
            int col = n0 + w*32 + nt*16 + (l & 15);
            int r0 = m0 + mt*16 + ((l >> 4) << 2);
            if constexpr (EPI == 0) {
                #pragma unroll
                for (int j = 0; j < 4; ++j)
                    outF[zO + (long)(r0 + j) * ors + col] = c[j];
            } else if constexpr (EPI == 1) {
                float bv = bias[col];
                #pragma unroll
                for (int j = 0; j < 4; ++j)
                    outB[zO + (long)(r0 + j) * ors + col] = f2bf(fmaxf(c[j] + bv, 0.f));
            } else {
                float bv = bias[col];
                float p0 = fmaxf(fmaxf(c[0], c[1]) + bv, 0.f);
                float p1 = fmaxf(fmaxf(c[2], c[3]) + bv, 0.f);
                int tp = r0 >> 1;
                outB[zO + (long)(tp + 1) * ors + col] = f2bf(p0);
                outB[zO + (long)(tp + 2) * ors + col] = f2bf(p1);
            }
        }
}

// ---------------- fp32 GEMM (x_proj / dt_proj path, precision-sensitive) ----------------
template<int ACT>   // 0 = none, 1 = softplus
__global__ __launch_bounds__(256) void k_gemm(const float* __restrict__ A, int lda,
                                              const float* __restrict__ WT,
                                              const float* __restrict__ bias,
                                              float* __restrict__ out,
                                              int M, int N, int K) {
    __shared__ float As[16][68];
    __shared__ float Bs[16][64];
    int n0 = blockIdx.x * 64, m0 = blockIdx.y * 64;
    int tid = threadIdx.x;
    int ti = tid >> 4, tj = tid & 15;
    float acc[4][4] = {};
    for (int k0 = 0; k0 < K; k0 += 16) {
        {
            int mm = tid >> 2, kq = tid & 3;
            float4 v = *(const float4*)&A[(long)(m0 + mm)*lda + k0 + kq*4];
            As[kq*4+0][mm] = v.x; As[kq*4+1][mm] = v.y;
            As[kq*4+2][mm] = v.z; As[kq*4+3][mm] = v.w;
        }
        {
            int kk = tid >> 4, n4 = tid & 15;
            float4 v = {0.f,0.f,0.f,0.f};
            if (n0 + n4*4 < N)
                v = *(const float4*)&WT[(long)(k0 + kk)*N + n0 + n4*4];
            *(float4*)&Bs[kk][n4*4] = v;
        }
        __syncthreads();
        #pragma unroll
        for (int kk = 0; kk < 16; ++kk) {
            float4 av = *(float4*)&As[kk][ti*4];
            float4 bv = *(float4*)&Bs[kk][tj*4];
            acc[0][0] += av.x*bv.x; acc[0][1] += av.x*bv.y; acc[0][2] += av.x*bv.z; acc[0][3] += av.x*bv.w;
            acc[1][0] += av.y*bv.x; acc[1][1] += av.y*bv.y; acc[1][2] += av.y*bv.z; acc[1][3] += av.y*bv.w;
            acc[2][0] += av.z*bv.x; acc[2][1] += av.z*bv.y; acc[2][2] += av.z*bv.z; acc[2][3] += av.z*bv.w;
            acc[3][0] += av.w*bv.x; acc[3][1] += av.w*bv.y; acc[3][2] += av.w*bv.z; acc[3][3] += av.w*bv.w;
        }
        __syncthreads();
    }
    if (n0 + tj*4 >= N) return;
    float4 bv = {0.f,0.f,0.f,0.f};
    if (bias) bv = *(const float4*)&bias[n0 + tj*4];
    #pragma unroll
    for (int i = 0; i < 4; ++i) {
        int m = m0 + ti*4 + i;
        float4 v;
        v.x = acc[i][0] + bv.x; v.y = acc[i][1] + bv.y;
        v.z = acc[i][2] + bv.z; v.w = acc[i][3] + bv.w;
        if (ACT == 1) {
            v.x = (v.x > 20.f) ? v.x : log1pf(__expf(v.x));
            v.y = (v.y > 20.f) ? v.y : log1pf(__expf(v.y));
            v.z = (v.z > 20.f) ? v.z : log1pf(__expf(v.z));
            v.w = (v.w > 20.f) ? v.w : log1pf(__expf(v.w));
        }
        *(float4*)&out[(long)m*N + n0 + tj*4] = v;
    }
}

// ---------------- causal depthwise conv (k=4) + SiLU : LDS weights, 4t/thread ----------------
__global__ __launch_bounds__(256) void k_dwconv(const float* __restrict__ xz,
                                                const float* __restrict__ wdw,
                                                const float* __restrict__ bdw,
                                                float* __restrict__ xout) {
    __shared__ float wk[4][512];
    __shared__ float bs[512];
    int tid = threadIdx.x;
    for (int e = tid; e < 2048; e += 256) {
        int k = e >> 9, d = e & 511;
        wk[k][d] = wdw[d*4 + k];
    }
    bs[tid] = bdw[tid];
    bs[tid + 256] = bdw[tid + 256];
    __syncthreads();

    int idx = blockIdx.x * 256 + tid;        // (b, tg, d4): 8*512*128
    int d4 = idx & 127;
    int tg = (idx >> 7) & 511;
    int b  = idx >> 16;
    int d0 = d4 * 4;
    int t0 = tg * 4;

    float4 x[7];
    #pragma unroll
    for (int i = 0; i < 7; ++i) {
        int t = t0 - 3 + i;
        x[i] = (t >= 0) ? *(const float4*)&xz[((long)(b*Lh + t))*1024 + d0]
                        : (float4){0.f, 0.f, 0.f, 0.f};
    }
    float4 w[4];
    #pragma unroll
    for (int k = 0; k < 4; ++k) w[k] = *(float4*)&wk[k][d0];
    float4 bias4 = *(float4*)&bs[d0];

    #pragma unroll
    for (int j = 0; j < 4; ++j) {
        float4 a = bias4;
        #pragma unroll
        for (int k = 0; k < 4; ++k) {
            float4 v = x[j + k];
            a.x += v.x * w[k].x; a.y += v.y * w[k].y;
            a.z += v.z * w[k].z; a.w += v.w * w[k].w;
        }
        a.x = a.x / (1.f + __expf(-a.x));
        a.y = a.y / (1.f + __expf(-a.y));
        a.z = a.z / (1.f + __expf(-a.z));
        a.w = a.w / (1.f + __expf(-a.w));
        *(float4*)&xout[((long)(b*Lh + t0 + j))*512 + d0] = a;
    }
}

// ---------------- chunked selective scan ----------------
// Phase A: local scan (h=0); emits hend, P=q, S[n]=Σ gate·C_n·q_n, ypart=Σ gate·(C·h_local + x·Dp)
__global__ __launch_bounds__(256) void k_scan_a(const float* __restrict__ dt,
                                                const float* __restrict__ x,
                                                const float* __restrict__ xz,
                                                const float* __restrict__ dbc,
                                                const float* __restrict__ A_log,
                                                const float* __restrict__ Dp,
                                                float* __restrict__ hend,
                                                float* __restrict__ Pbuf,
                                                float* __restrict__ Sbuf,
                                                float* __restrict__ ypart) {
    __shared__ float4 Bs4[TC][4], Cs4[TC][4];
    int c = blockIdx.x;
    int b = blockIdx.z;
    int tid = threadIdx.x;
    int d = blockIdx.y * 256 + tid;
    for (int i = tid; i < TC*4; i += 256) {
        int tt = i >> 2, q = i & 3;
        long rb = ((long)b*Lh + c*TC + tt)*48;
        Bs4[tt][q] = *(const float4*)&dbc[rb + 16 + q*4];
        Cs4[tt][q] = *(const float4*)&dbc[rb + 32 + q*4];
    }
    __syncthreads();
    float A_[16];
    #pragma unroll
    for (int n = 0; n < 16; ++n) A_[n] = -__expf(A_log[d*16 + n]);
    float h[16], q[16], S[16];
    #pragma unroll
    for (int n = 0; n < 16; ++n) { h[n] = 0.f; q[n] = 1.f; S[n] = 0.f; }
    float Dpv = Dp[d];
    float yp = 0.f;
    long base  = ((long)b*Lh + c*TC)*512 + d;
    long zbase = ((long)b*Lh + c*TC)*1024 + 512 + d;
    for (int tt = 0; tt < TC; ++tt) {
        float dtv = dt[base + (long)tt*512];
        float xv  = x[base + (long)tt*512];
        float zv  = xz[zbase + (long)tt*1024];
        float u = dtv * xv;
        float gate = zv / (1.f + __expf(-zv));
        float Bv[16], Cv[16];
        *(float4*)&Bv[0]  = Bs4[tt][0]; *(float4*)&Bv[4]  = Bs4[tt][1];
        *(float4*)&Bv[8]  = Bs4[tt][2]; *(float4*)&Bv[12] = Bs4[tt][3];
        *(float4*)&Cv[0]  = Cs4[tt][0]; *(float4*)&Cv[4]  = Cs4[tt][1];
        *(float4*)&Cv[8]  = Cs4[tt][2]; *(float4*)&Cv[12] = Cs4[tt][3];
        float p = 0.f;
        #pragma unroll
        for (int n = 0; n < 16; ++n) {
            float dA = __expf(dtv * A_[n]);
            h[n] = h[n] * dA + u * Bv[n];
            q[n] *= dA;
            p += h[n] * Cv[n];
            S[n] += (gate * Cv[n]) * q[n];
        }
        yp += gate * (p + xv * Dpv);
    }
    long o = (((long)b*Din + d)*NCH + c)*16;
    #pragma unroll
    for (int n = 0; n < 16; ++n) hend[o + n] = h[n];
    #pragma unroll
    for (int n = 0; n < 16; ++n) Pbuf[o + n] = q[n];
    #pragma unroll
    for (int n = 0; n < 16; ++n) Sbuf[o + n] = S[n];
    ypart[((long)b*Din + d)*NCH + c] = yp;
}

// Phase B: serial combine over chunks -> carry-in hin
__global__ void k_scan_b(const float* __restrict__ hend, const float* __restrict__ Pbuf,
                         float* __restrict__ hin) {
    int idx = blockIdx.x * 256 + threadIdx.x;
    int n = idx & 15; long bd = idx >> 4;
    long base = bd * NCH * 16 + n;
    float h = 0.f;
    for (int c = 0; c < NCH; ++c) {
        hin[base + c*16] = h;
        h = hend[base + c*16] + Pbuf[base + c*16] * h;
    }
}

// Phase C-lite: per (b,d): ym = Σ_c [ ypart_c + dot(S_c, hin_c) ]. One wave per (b,d), lane = c.
__global__ __launch_bounds__(256) void k_scan_cl(const float* __restrict__ Sbuf,
                                                 const float* __restrict__ hin,
                                                 const float* __restrict__ ypart,
                                                 float* __restrict__ ym) {
    int idx = blockIdx.x * 256 + threadIdx.x;   // 8*512*64 = 262144
    int c = idx & 63;
    long bd = idx >> 6;
    long o = (bd * NCH + c) * 16;
    float v = ypart[bd * NCH + c];
    #pragma unroll
    for (int qq = 0; qq < 4; ++qq) {
        float4 s = *(const float4*)&Sbuf[o + qq*4];
        float4 hi = *(const float4*)&hin[o + qq*4];
        v += s.x*hi.x + s.y*hi.y + s.z*hi.z + s.w*hi.w;
    }
    v += __shfl_xor(v, 1);
    v += __shfl_xor(v, 2);
    v += __shfl_xor(v, 4);
    v += __shfl_xor(v, 8);
    v += __shfl_xor(v, 16);
    v += __shfl_xor(v, 32);
    if (c == 0) ym[bd] = v;
}

// ---------------- tail: xm = (ym/2048) @ ow^T ; logits = xm @ fcw^T + fcb ----------------
__global__ void k_tail(const float* __restrict__ ym, const float* __restrict__ ow,
                       const float* __restrict__ fcw, const float* __restrict__ fcb,
                       float* __restrict__ out) {
    __shared__ float yls[512];
    __shared__ float xs[256];
    int b = blockIdx.x, c = threadIdx.x;
    yls[c] = ym[b*512 + c];
    yls[c + 256] = ym[b*512 + 256 + c];
    __syncthreads();
    float s = 0.f;
    for (int d = 0; d < 512; ++d) s += yls[d] * ow[c*512 + d];
    xs[c] = s * (1.f / 2048.f);
    __syncthreads();
    if (c < 10) {
        float t = fcb[c];
        for (int k = 0; k < 256; ++k) t += xs[k] * fcw[c*256 + k];
        out[b*10 + c] = t;
    }
}

extern "C" void kernel_launch(void* const* d_in, const int* in_sizes, int n_in,
                              void* d_out, int out_size, void* d_ws, size_t ws_size,
                              hipStream_t stream) {
    const int*   tok  = (const int*)d_in[0];
    const float* emb  = (const float*)d_in[1];
    const float* w1   = (const float*)d_in[2];
    const float* b1   = (const float*)d_in[3];
    const float* w2   = (const float*)d_in[4];
    const float* b2   = (const float*)d_in[5];
    const float* win  = (const float*)d_in[6];
    const float* wdw  = (const float*)d_in[7];
    const float* bdw  = (const float*)d_in[8];
    const float* xw   = (const float*)d_in[9];
    const float* dtw  = (const float*)d_in[10];
    const float* dtb  = (const float*)d_in[11];
    const float* alog = (const float*)d_in[12];
    const float* Dp   = (const float*)d_in[13];
    const float* ow   = (const float*)d_in[14];
    const float* fcw  = (const float*)d_in[15];
    const float* fcb  = (const float*)d_in[16];
    float* ws  = (float*)d_ws;
    float* out = (float*)d_out;

    float* wtx   = ws + o_wtx;
    float* wtdt  = ws + o_wtdt;
    short* wt1t  = (short*)(ws + o_bf);
    short* wt2t  = wt1t + 163840;
    short* wtint = wt2t + 98304;
    short* xeb   = (short*)(ws + o_xeb);
    short* out1b = (short*)(ws + o_out1b);
    short* ub    = (short*)(ws + o_ub);
    float* xz    = ws + o_xz;
    float* xbuf  = ws + o_xbuf;
    float* dbc   = ws + o_dbc;
    float* dtbuf = ws + o_dt;
    float* hend  = ws + o_hend;
    float* Pbuf  = ws + o_P;
    float* hin   = ws + o_hin;
    float* ym    = ws + o_ym;
    float* Sbuf  = ws + o_S;
    float* ypart = ws + o_yp;

    // 1. weight prep
    k_prep<<<2176, 256, 0, stream>>>(w1, w2, win, xw, dtw, ws);
    // 2. embedding -> padded bf16 xe [8][4100][256]
    k_embed<<<4100, 256, 0, stream>>>(tok, emb, xeb);
    // 3. zero pad rows of out1b
    k_zpad<<<1, 256, 0, stream>>>(out1b);
    // 4. conv1 (K=1280, C=256) + relu + pool -> out1b bf16 [8][2050][128]
    k_mgemm<5, 4, 2><<<dim3(64, 1, 8), 256, 0, stream>>>(
        xeb, 256, 4100L*256, wt1t, 1280, b1, out1b, nullptr, 128, 2050L*128);
    // 5. conv2 (K=384, C=128) + relu -> ub bf16 [16384][256]
    k_mgemm<3, 2, 1><<<dim3(32, 2, 8), 256, 0, stream>>>(
        out1b, 128, 2050L*128, wt2t, 384, b2, ub, nullptr, 256, 2048L*256);
    // 6. in_proj (K=256) -> xz fp32 [16384][1024]
    k_mgemm<1, 4, 0><<<dim3(256, 8, 1), 256, 0, stream>>>(
        ub, 256, 0, wtint, 256, nullptr, nullptr, xz, 1024, 0);
    // 7. depthwise conv + silu -> xbuf fp32 [16384][512]
    k_dwconv<<<2048, 256, 0, stream>>>(xz, wdw, bdw, xbuf);
    // 8. x_proj (fp32) -> dbc [16384][48]
    k_gemm<0><<<dim3(1, M2/64), 256, 0, stream>>>(xbuf, Din, wtx, nullptr, dbc, M2, 48, Din);
    // 9. dt_proj + softplus (fp32) -> dtbuf [16384][512]
    k_gemm<1><<<dim3(8, M2/64), 256, 0, stream>>>(dbc, 48, wtdt, dtb, dtbuf, M2, 512, 16);
    // 10. chunked selective scan: A emits (hend,P,S,ypart); B combines; C-lite reduces
    k_scan_a<<<dim3(NCH, 2, Bn), 256, 0, stream>>>(dtbuf, xbuf, xz, dbc, alog, Dp,
                                                   hend, Pbuf, Sbuf, ypart);
    k_scan_b<<<(Bn*Din*Nst)/256, 256, 0, stream>>>(hend, Pbuf, hin);
    k_scan_cl<<<(Bn*Din*NCH)/256, 256, 0, stream>>>(Sbuf, hin, ypart, ym);
    // 11. tail: out_proj on means + fc -> logits
    k_tail<<<8, 256, 0, stream>>>(ym, ow, fcw, fcb, out);
}

// Round 12
// 344.469 us; speedup vs baseline: 3.5021x; 1.0274x over previous
//
#include <hip/hip_runtime.h>
#include <hip/hip_bf16.h>

// ---------------- problem constants ----------------
constexpr int Bn   = 8;
constexpr int L    = 4096;
constexpr int E    = 256;
constexpr int Lh   = 2048;
constexpr int C1n  = 128;
constexpr int Dlat = 256;
constexpr int Din  = 512;
constexpr int Nst  = 16;
constexpr int M2   = Bn * Lh;   // 16384
constexpr int NCH  = 128;       // scan chunks
constexpr int TC   = 16;        // timesteps per chunk

// ---------------- workspace layout (float offsets) ----------------
constexpr long o_wtx   = 0;                         // [512][48] fp32
constexpr long o_wtdt  = o_wtx  + 512L*48;          // [16][512] fp32
constexpr long o_bf    = o_wtdt + 16L*512;          // bf16 weights region (shorts)
constexpr long o_xeb   = o_bf    + 524288/2;        // xe bf16 [8][4100][256] padded
constexpr long o_out1b = o_xeb   + (8L*4100*256)/2; // out1 bf16 [8][2050][128] padded
constexpr long o_ub    = o_out1b + (8L*2050*128)/2; // u bf16 [16384][256]
constexpr long o_xz    = o_ub    + (16384L*256)/2;  // fp32 [16384][1024]
constexpr long o_xbuf  = o_xz    + 16384L*1024;     // fp32 [16384][512]
constexpr long o_dbc   = o_xbuf  + 16384L*512;      // fp32 [16384][48]
constexpr long o_hend  = o_dbc   + 16384L*48;       // [8][512][128][16]
constexpr long o_P     = o_hend  + 8L*512*NCH*16;
constexpr long o_S     = o_P     + 8L*512*NCH*16;
constexpr long o_ym    = o_S     + 8L*512*NCH*16;   // fp32 [8][512]
constexpr long o_yp    = o_ym    + 8L*512;          // [8][512][128]

typedef __attribute__((ext_vector_type(8))) short bf8_t;
typedef __attribute__((ext_vector_type(4))) float f4_t;

__device__ inline short f2bf(float f) {
    unsigned int u = __float_as_uint(f);
    unsigned int r = (u + 0x7FFFu + ((u >> 16) & 1u)) >> 16;
    return (short)r;
}

// ---------------- weight prep: fp32 transposes + bf16 [N][K] transposes ----------------
__global__ void k_prep(const float* __restrict__ w1, const float* __restrict__ w2,
                       const float* __restrict__ win, const float* __restrict__ xw,
                       const float* __restrict__ dtw, float* __restrict__ ws) {
    int idx = blockIdx.x * 256 + threadIdx.x;
    if (idx < 24576) {                        // wtx[k][n] = xw[n][k]  (fp32)
        int n_ = idx % 48; int k = idx / 48;
        ws[o_wtx + idx] = xw[n_*512 + k];
    } else if (idx < 32768) {                 // wtdt[k][n] = dtw[n][k] (fp32)
        int j = idx - 24576;
        int n_ = j & 511; int k = j >> 9;
        ws[o_wtdt + j] = dtw[n_*16 + k];
    } else if (idx < 557056) {                // bf16 region
        int j = idx - 32768;
        short* wsS = (short*)(ws + o_bf);
        if (j < 163840) {                     // wt1t[n][s*256+c] = w1[n][c][s]
            int n_ = j / 1280; int r = j - n_*1280; int s = r >> 8; int c = r & 255;
            wsS[j] = f2bf(w1[(n_*256 + c)*5 + s]);
        } else if (j < 262144) {              // wt2t[n][s*128+c] = w2[n][c][s]
            int jj = j - 163840;
            int n_ = jj / 384; int r = jj - n_*384; int s = r >> 7; int c = r & 127;
            wsS[j] = f2bf(w2[(n_*128 + c)*3 + s]);
        } else {                              // wtint[n][k] = win[n][k]
            int jj = j - 262144;
            int n_ = jj >> 8; int k = jj & 255;
            wsS[j] = f2bf(win[n_*256 + k]);
        }
    }
}

// ---------------- embedding gather -> padded bf16 [8][4100][256] ----------------
__global__ void k_embed(const int* __restrict__ tok, const float* __restrict__ emb,
                        short* __restrict__ xeb) {
    int idx = blockIdx.x * 256 + threadIdx.x;
    int r = idx >> 5;
    int c8 = (idx & 31) << 3;
    int b = r / 4100; int tr = r - b*4100;
    bf8_t v = {0,0,0,0,0,0,0,0};
    if (tr >= 2 && tr < 4098) {
        int t = tok[b*4096 + tr - 2];
        const float* e = emb + (long)t*256 + c8;
        #pragma unroll
        for (int i = 0; i < 8; ++i) v[i] = f2bf(e[i]);
    }
    *(bf8_t*)&xeb[(long)r*256 + c8] = v;
}

// ---------------- zero pad rows of out1b ----------------
__global__ void k_zpad(short* __restrict__ out1b) {
    int i = threadIdx.x;
    for (int j = i; j < 2048; j += 256) {
        int b = j >> 8; int rsel = (j >> 7) & 1; int c = j & 127;
        long row = (long)b*2050 + (rsel ? 2049 : 0);
        out1b[row*128 + c] = 0;
    }
}

// ---------------- LDS-staged double-buffered MFMA GEMM ----------------
template<int SHIFTS, int TPS, int EPI>
__global__ __launch_bounds__(256) void k_mgemm(const short* __restrict__ A, int ars, long batchA,
                                               const short* __restrict__ Bt, int ktot,
                                               const float* __restrict__ bias,
                                               short* __restrict__ outB, float* __restrict__ outF,
                                               int ors, long batchOut) {
    constexpr int KT = SHIFTS * TPS;
    constexpr int C  = TPS * 64;
    __shared__ short As[2][64][68];
    __shared__ short Bs[2][128][68];
    int tid = threadIdx.x;
    int l = tid & 63, w = tid >> 6;
    int m0 = blockIdx.x * 64;
    int n0 = blockIdx.y * 128;
    long zA = (long)blockIdx.z * batchA;
    long zO = (long)blockIdx.z * batchOut;

    bf8_t aReg[2], bReg[4];

    auto gload = [&](int kt) {
        int s = kt / TPS, c0 = (kt % TPS) * 64;
        const short* Ab = A + zA + (long)(m0 + s) * ars + c0;
        #pragma unroll
        for (int j = 0; j < 2; ++j) {
            int idx = tid + j*256;
            int r = idx >> 3, cc = (idx & 7) * 8;
            aReg[j] = *(const bf8_t*)&Ab[(long)r * ars + cc];
        }
        const short* Bb = Bt + (long)n0 * ktot + s * C + c0;
        #pragma unroll
        for (int j = 0; j < 4; ++j) {
            int idx = tid + j*256;
            int r = idx >> 3, cc = (idx & 7) * 8;
            bReg[j] = *(const bf8_t*)&Bb[(long)r * ktot + cc];
        }
    };
    auto lwrite = [&](int buf) {
        #pragma unroll
        for (int j = 0; j < 2; ++j) {
            int idx = tid + j*256;
            int r = idx >> 3, cc = (idx & 7) * 8;
            *(bf8_t*)&As[buf][r][cc] = aReg[j];
        }
        #pragma unroll
        for (int j = 0; j < 4; ++j) {
            int idx = tid + j*256;
            int r = idx >> 3, cc = (idx & 7) * 8;
            *(bf8_t*)&Bs[buf][r][cc] = bReg[j];
        }
    };

    f4_t acc[4][2];
    #pragma unroll
    for (int m = 0; m < 4; ++m)
        #pragma unroll
        for (int n = 0; n < 2; ++n) acc[m][n] = (f4_t){0.f, 0.f, 0.f, 0.f};

    gload(0);
    lwrite(0);
    __syncthreads();
    for (int kt = 0; kt < KT; ++kt) {
        int buf = kt & 1;
        if (kt + 1 < KT) gload(kt + 1);
        #pragma unroll
        for (int ks = 0; ks < 2; ++ks) {
            int kk = ks*32 + ((l >> 4) << 3);
            bf8_t a[4], b[2];
            #pragma unroll
            for (int m = 0; m < 4; ++m)
                a[m] = *(const bf8_t*)&As[buf][m*16 + (l & 15)][kk];
            #pragma unroll
            for (int n = 0; n < 2; ++n)
                b[n] = *(const bf8_t*)&Bs[buf][w*32 + n*16 + (l & 15)][kk];
            #pragma unroll
            for (int m = 0; m < 4; ++m)
                #pragma unroll
                for (int n = 0; n < 2; ++n)
                    acc[m][n] = __builtin_amdgcn_mfma_f32_16x16x32_bf16(a[m], b[n], acc[m][n], 0, 0, 0);
        }
        if (kt + 1 < KT) {
            lwrite(buf ^ 1);
            __syncthreads();
        }
    }

    #pragma unroll
    for (int mt = 0; mt < 4; ++mt)
        #pragma unroll
        for (int nt = 0; nt < 2; ++nt) {
            f4_t c = acc[mt][nt];
            int col = n0 + w*32 + nt*16 + (l & 15);
            int r0 = m0 + mt*16 + ((l >> 4) << 2);
            if constexpr (EPI == 0) {
                #pragma unroll
                for (int j = 0; j < 4; ++j)
                    outF[zO + (long)(r0 + j) * ors + col] = c[j];
            } else if constexpr (EPI == 1) {
                float bv = bias[col];
                #pragma unroll
                for (int j = 0; j < 4; ++j)
                    outB[zO + (long)(r0 + j) * ors + col] = f2bf(fmaxf(c[j] + bv, 0.f));
            } else {
                float bv = bias[col];
                float p0 = fmaxf(fmaxf(c[0], c[1]) + bv, 0.f);
                float p1 = fmaxf(fmaxf(c[2], c[3]) + bv, 0.f);
                int tp = r0 >> 1;
                outB[zO + (long)(tp + 1) * ors + col] = f2bf(p0);
                outB[zO + (long)(tp + 2) * ors + col] = f2bf(p1);
            }
        }
}

// ---------------- fp32 GEMM (x_proj, precision-sensitive) ----------------
template<int ACT>
__global__ __launch_bounds__(256) void k_gemm(const float* __restrict__ A, int lda,
                                              const float* __restrict__ WT,
                                              const float* __restrict__ bias,
                                              float* __restrict__ out,
                                              int M, int N, int K) {
    __shared__ float As[16][68];
    __shared__ float Bs[16][64];
    int n0 = blockIdx.x * 64, m0 = blockIdx.y * 64;
    int tid = threadIdx.x;
    int ti = tid >> 4, tj = tid & 15;
    float acc[4][4] = {};
    for (int k0 = 0; k0 < K; k0 += 16) {
        {
            int mm = tid >> 2, kq = tid & 3;
            float4 v = *(const float4*)&A[(long)(m0 + mm)*lda + k0 + kq*4];
            As[kq*4+0][mm] = v.x; As[kq*4+1][mm] = v.y;
            As[kq*4+2][mm] = v.z; As[kq*4+3][mm] = v.w;
        }
        {
            int kk = tid >> 4, n4 = tid & 15;
            float4 v = {0.f,0.f,0.f,0.f};
            if (n0 + n4*4 < N)
                v = *(const float4*)&WT[(long)(k0 + kk)*N + n0 + n4*4];
            *(float4*)&Bs[kk][n4*4] = v;
        }
        __syncthreads();
        #pragma unroll
        for (int kk = 0; kk < 16; ++kk) {
            float4 av = *(float4*)&As[kk][ti*4];
            float4 bv = *(float4*)&Bs[kk][tj*4];
            acc[0][0] += av.x*bv.x; acc[0][1] += av.x*bv.y; acc[0][2] += av.x*bv.z; acc[0][3] += av.x*bv.w;
            acc[1][0] += av.y*bv.x; acc[1][1] += av.y*bv.y; acc[1][2] += av.y*bv.z; acc[1][3] += av.y*bv.w;
            acc[2][0] += av.z*bv.x; acc[2][1] += av.z*bv.y; acc[2][2] += av.z*bv.z; acc[2][3] += av.z*bv.w;
            acc[3][0] += av.w*bv.x; acc[3][1] += av.w*bv.y; acc[3][2] += av.w*bv.z; acc[3][3] += av.w*bv.w;
        }
        __syncthreads();
    }
    if (n0 + tj*4 >= N) return;
    float4 bv = {0.f,0.f,0.f,0.f};
    if (bias) bv = *(const float4*)&bias[n0 + tj*4];
    #pragma unroll
    for (int i = 0; i < 4; ++i) {
        int m = m0 + ti*4 + i;
        float4 v;
        v.x = acc[i][0] + bv.x; v.y = acc[i][1] + bv.y;
        v.z = acc[i][2] + bv.z; v.w = acc[i][3] + bv.w;
        if (ACT == 1) {
            v.x = (v.x > 20.f) ? v.x : log1pf(__expf(v.x));
            v.y = (v.y > 20.f) ? v.y : log1pf(__expf(v.y));
            v.z = (v.z > 20.f) ? v.z : log1pf(__expf(v.z));
            v.w = (v.w > 20.f) ? v.w : log1pf(__expf(v.w));
        }
        *(float4*)&out[(long)m*N + n0 + tj*4] = v;
    }
}

// ---------------- causal depthwise conv (k=4) + SiLU : LDS weights, 4t/thread ----------------
__global__ __launch_bounds__(256) void k_dwconv(const float* __restrict__ xz,
                                                const float* __restrict__ wdw,
                                                const float* __restrict__ bdw,
                                                float* __restrict__ xout) {
    __shared__ float wk[4][512];
    __shared__ float bs[512];
    int tid = threadIdx.x;
    for (int e = tid; e < 2048; e += 256) {
        int k = e >> 9, d = e & 511;
        wk[k][d] = wdw[d*4 + k];
    }
    bs[tid] = bdw[tid];
    bs[tid + 256] = bdw[tid + 256];
    __syncthreads();

    int idx = blockIdx.x * 256 + tid;        // (b, tg, d4): 8*512*128
    int d4 = idx & 127;
    int tg = (idx >> 7) & 511;
    int b  = idx >> 16;
    int d0 = d4 * 4;
    int t0 = tg * 4;

    float4 x[7];
    #pragma unroll
    for (int i = 0; i < 7; ++i) {
        int t = t0 - 3 + i;
        x[i] = (t >= 0) ? *(const float4*)&xz[((long)(b*Lh + t))*1024 + d0]
                        : (float4){0.f, 0.f, 0.f, 0.f};
    }
    float4 w[4];
    #pragma unroll
    for (int k = 0; k < 4; ++k) w[k] = *(float4*)&wk[k][d0];
    float4 bias4 = *(float4*)&bs[d0];

    #pragma unroll
    for (int j = 0; j < 4; ++j) {
        float4 a = bias4;
        #pragma unroll
        for (int k = 0; k < 4; ++k) {
            float4 v = x[j + k];
            a.x += v.x * w[k].x; a.y += v.y * w[k].y;
            a.z += v.z * w[k].z; a.w += v.w * w[k].w;
        }
        a.x = a.x / (1.f + __expf(-a.x));
        a.y = a.y / (1.f + __expf(-a.y));
        a.z = a.z / (1.f + __expf(-a.z));
        a.w = a.w / (1.f + __expf(-a.w));
        *(float4*)&xout[((long)(b*Lh + t0 + j))*512 + d0] = a;
    }
}

// ---------------- chunked selective scan ----------------
// Phase A (dt_proj fused): local scan (h=0); emits hend, P=q, S[n]=Σ gate·C_n·q_n,
// ypart=Σ gate·(C·h_local + x·Dp).  dt = softplus(dot16(dbc[:,0:16], wtdt[:,d]) + dtb[d]).
__global__ __launch_bounds__(256) void k_scan_a(const float* __restrict__ x,
                                                const float* __restrict__ xz,
                                                const float* __restrict__ dbc,
                                                const float* __restrict__ wtdt,
                                                const float* __restrict__ dtb,
                                                const float* __restrict__ A_log,
                                                const float* __restrict__ Dp,
                                                float* __restrict__ hend,
                                                float* __restrict__ Pbuf,
                                                float* __restrict__ Sbuf,
                                                float* __restrict__ ypart) {
    __shared__ float4 Ds4[TC][4], Bs4[TC][4], Cs4[TC][4];
    int c = blockIdx.x;
    int b = blockIdx.z;
    int tid = threadIdx.x;
    int d = blockIdx.y * 256 + tid;
    for (int i = tid; i < TC*4; i += 256) {
        int tt = i >> 2, qq = i & 3;
        long rb = ((long)b*Lh + c*TC + tt)*48;
        Ds4[tt][qq] = *(const float4*)&dbc[rb + qq*4];
        Bs4[tt][qq] = *(const float4*)&dbc[rb + 16 + qq*4];
        Cs4[tt][qq] = *(const float4*)&dbc[rb + 32 + qq*4];
    }
    __syncthreads();
    float A_[16], wdt[16];
    #pragma unroll
    for (int n = 0; n < 16; ++n) A_[n] = -__expf(A_log[d*16 + n]);
    #pragma unroll
    for (int n = 0; n < 16; ++n) wdt[n] = wtdt[n*512 + d];
    float dtbd = dtb[d];
    float h[16], q[16], S[16];
    #pragma unroll
    for (int n = 0; n < 16; ++n) { h[n] = 0.f; q[n] = 1.f; S[n] = 0.f; }
    float Dpv = Dp[d];
    float yp = 0.f;
    long base  = ((long)b*Lh + c*TC)*512 + d;
    long zbase = ((long)b*Lh + c*TC)*1024 + 512 + d;
    for (int tt = 0; tt < TC; ++tt) {
        float dr[16];
        *(float4*)&dr[0]  = Ds4[tt][0]; *(float4*)&dr[4]  = Ds4[tt][1];
        *(float4*)&dr[8]  = Ds4[tt][2]; *(float4*)&dr[12] = Ds4[tt][3];
        float raw = dtbd;
        #pragma unroll
        for (int k = 0; k < 16; ++k) raw += dr[k] * wdt[k];
        float dtv = (raw > 20.f) ? raw : log1pf(__expf(raw));
        float xv  = x[base + (long)tt*512];
        float zv  = xz[zbase + (long)tt*1024];
        float u = dtv * xv;
        float gate = zv / (1.f + __expf(-zv));
        float Bv[16], Cv[16];
        *(float4*)&Bv[0]  = Bs4[tt][0]; *(float4*)&Bv[4]  = Bs4[tt][1];
        *(float4*)&Bv[8]  = Bs4[tt][2]; *(float4*)&Bv[12] = Bs4[tt][3];
        *(float4*)&Cv[0]  = Cs4[tt][0]; *(float4*)&Cv[4]  = Cs4[tt][1];
        *(float4*)&Cv[8]  = Cs4[tt][2]; *(float4*)&Cv[12] = Cs4[tt][3];
        float p = 0.f;
        #pragma unroll
        for (int n = 0; n < 16; ++n) {
            float dA = __expf(dtv * A_[n]);
            h[n] = h[n] * dA + u * Bv[n];
            q[n] *= dA;
            p += h[n] * Cv[n];
            S[n] += (gate * Cv[n]) * q[n];
        }
        yp += gate * (p + xv * Dpv);
    }
    long o = (((long)b*Din + d)*NCH + c)*16;
    #pragma unroll
    for (int n = 0; n < 16; ++n) hend[o + n] = h[n];
    #pragma unroll
    for (int n = 0; n < 16; ++n) Pbuf[o + n] = q[n];
    #pragma unroll
    for (int n = 0; n < 16; ++n) Sbuf[o + n] = S[n];
    ypart[((long)b*Din + d)*NCH + c] = yp;
}

// Phase BC fused: lane (b,d,n) serially combines chunks, accumulating S·h_in inline;
// then adds ypart and 16-lane shuffle-reduces -> ym[b][d].
__global__ __launch_bounds__(256) void k_scan_bc(const float* __restrict__ hend,
                                                 const float* __restrict__ Pbuf,
                                                 const float* __restrict__ Sbuf,
                                                 const float* __restrict__ ypart,
                                                 float* __restrict__ ym) {
    int idx = blockIdx.x * 256 + threadIdx.x;   // (b,d,n): 65536
    int n = idx & 15; long bd = idx >> 4;
    long base = bd * NCH * 16 + n;
    float h = 0.f, acc = 0.f;
    for (int c = 0; c < NCH; ++c) {
        long o = base + (long)c*16;
        acc += Sbuf[o] * h;                  // h = carry-in for chunk c
        h = hend[o] + Pbuf[o] * h;
    }
    #pragma unroll
    for (int k = 0; k < 8; ++k)
        acc += ypart[bd * NCH + n + k*16];
    acc += __shfl_xor(acc, 1);
    acc += __shfl_xor(acc, 2);
    acc += __shfl_xor(acc, 4);
    acc += __shfl_xor(acc, 8);
    if (n == 0) ym[bd] = acc;
}

// ---------------- tail: xm = (ym/2048) @ ow^T ; logits = xm @ fcw^T + fcb ----------------
__global__ void k_tail(const float* __restrict__ ym, const float* __restrict__ ow,
                       const float* __restrict__ fcw, const float* __restrict__ fcb,
                       float* __restrict__ out) {
    __shared__ float yls[512];
    __shared__ float xs[256];
    int b = blockIdx.x, c = threadIdx.x;
    yls[c] = ym[b*512 + c];
    yls[c + 256] = ym[b*512 + 256 + c];
    __syncthreads();
    float s = 0.f;
    for (int d = 0; d < 512; ++d) s += yls[d] * ow[c*512 + d];
    xs[c] = s * (1.f / 2048.f);
    __syncthreads();
    if (c < 10) {
        float t = fcb[c];
        for (int k = 0; k < 256; ++k) t += xs[k] * fcw[c*256 + k];
        out[b*10 + c] = t;
    }
}

extern "C" void kernel_launch(void* const* d_in, const int* in_sizes, int n_in,
                              void* d_out, int out_size, void* d_ws, size_t ws_size,
                              hipStream_t stream) {
    const int*   tok  = (const int*)d_in[0];
    const float* emb  = (const float*)d_in[1];
    const float* w1   = (const float*)d_in[2];
    const float* b1   = (const float*)d_in[3];
    const float* w2   = (const float*)d_in[4];
    const float* b2   = (const float*)d_in[5];
    const float* win  = (const float*)d_in[6];
    const float* wdw  = (const float*)d_in[7];
    const float* bdw  = (const float*)d_in[8];
    const float* xw   = (const float*)d_in[9];
    const float* dtw  = (const float*)d_in[10];
    const float* dtb  = (const float*)d_in[11];
    const float* alog = (const float*)d_in[12];
    const float* Dp   = (const float*)d_in[13];
    const float* ow   = (const float*)d_in[14];
    const float* fcw  = (const float*)d_in[15];
    const float* fcb  = (const float*)d_in[16];
    float* ws  = (float*)d_ws;
    float* out = (float*)d_out;

    float* wtx   = ws + o_wtx;
    float* wtdt  = ws + o_wtdt;
    short* wt1t  = (short*)(ws + o_bf);
    short* wt2t  = wt1t + 163840;
    short* wtint = wt2t + 98304;
    short* xeb   = (short*)(ws + o_xeb);
    short* out1b = (short*)(ws + o_out1b);
    short* ub    = (short*)(ws + o_ub);
    float* xz    = ws + o_xz;
    float* xbuf  = ws + o_xbuf;
    float* dbc   = ws + o_dbc;
    float* hend  = ws + o_hend;
    float* Pbuf  = ws + o_P;
    float* Sbuf  = ws + o_S;
    float* ym    = ws + o_ym;
    float* ypart = ws + o_yp;

    // 1. weight prep
    k_prep<<<2176, 256, 0, stream>>>(w1, w2, win, xw, dtw, ws);
    // 2. embedding -> padded bf16 xe [8][4100][256]
    k_embed<<<4100, 256, 0, stream>>>(tok, emb, xeb);
    // 3. zero pad rows of out1b
    k_zpad<<<1, 256, 0, stream>>>(out1b);
    // 4. conv1 (K=1280, C=256) + relu + pool -> out1b bf16 [8][2050][128]
    k_mgemm<5, 4, 2><<<dim3(64, 1, 8), 256, 0, stream>>>(
        xeb, 256, 4100L*256, wt1t, 1280, b1, out1b, nullptr, 128, 2050L*128);
    // 5. conv2 (K=384, C=128) + relu -> ub bf16 [16384][256]
    k_mgemm<3, 2, 1><<<dim3(32, 2, 8), 256, 0, stream>>>(
        out1b, 128, 2050L*128, wt2t, 384, b2, ub, nullptr, 256, 2048L*256);
    // 6. in_proj (K=256) -> xz fp32 [16384][1024]
    k_mgemm<1, 4, 0><<<dim3(256, 8, 1), 256, 0, stream>>>(
        ub, 256, 0, wtint, 256, nullptr, nullptr, xz, 1024, 0);
    // 7. depthwise conv + silu -> xbuf fp32 [16384][512]
    k_dwconv<<<2048, 256, 0, stream>>>(xz, wdw, bdw, xbuf);
    // 8. x_proj (fp32) -> dbc [16384][48]
    k_gemm<0><<<dim3(1, M2/64), 256, 0, stream>>>(xbuf, Din, wtx, nullptr, dbc, M2, 48, Din);
    // 9. chunked selective scan (dt_proj fused): A emits (hend,P,S,ypart); BC combines+reduces
    k_scan_a<<<dim3(NCH, 2, Bn), 256, 0, stream>>>(xbuf, xz, dbc, wtdt, dtb, alog, Dp,
                                                   hend, Pbuf, Sbuf, ypart);
    k_scan_bc<<<(Bn*Din*Nst)/256, 256, 0, stream>>>(hend, Pbuf, Sbuf, ypart, ym);
    // 10. tail: out_proj on means + fc -> logits
    k_tail<<<8, 256, 0, stream>>>(ym, ow, fcw, fcb, out);
}

// Round 13
// 335.849 us; speedup vs baseline: 3.5920x; 1.0257x over previous
//
#include <hip/hip_runtime.h>
#include <hip/hip_bf16.h>

// ---------------- problem constants ----------------
constexpr int Bn   = 8;
constexpr int L    = 4096;
constexpr int E    = 256;
constexpr int Lh   = 2048;
constexpr int C1n  = 128;
constexpr int Dlat = 256;
constexpr int Din  = 512;
constexpr int Nst  = 16;
constexpr int M2   = Bn * Lh;   // 16384
constexpr int NCH  = 64;        // scan chunks
constexpr int TC   = 32;        // timesteps per chunk

// ---------------- workspace layout (float offsets) ----------------
constexpr long o_wtx   = 0;                         // [512][48] fp32
constexpr long o_aneg  = o_wtx  + 512L*48;          // [512][16] fp32 : -exp(A_log)
constexpr long o_bf    = o_aneg + 512L*16;          // bf16 weights region (shorts)
constexpr long o_xeb   = o_bf    + 524288/2;        // xe bf16 [8][4100][256] padded
constexpr long o_out1b = o_xeb   + (8L*4100*256)/2; // out1 bf16 [8][2050][128] padded
constexpr long o_ub    = o_out1b + (8L*2050*128)/2; // u bf16 [16384][256]
constexpr long o_xz    = o_ub    + (16384L*256)/2;  // fp32 [16384][1024]
constexpr long o_xbuf  = o_xz    + 16384L*1024;     // fp32 [16384][512]
constexpr long o_dbc   = o_xbuf  + 16384L*512;      // fp32 [16384][48]
constexpr long o_hend  = o_dbc   + 16384L*48;       // [8][64][512][16]
constexpr long o_P     = o_hend  + 8L*NCH*512*16;
constexpr long o_S     = o_P     + 8L*NCH*512*16;
constexpr long o_ym    = o_S     + 8L*NCH*512*16;   // fp32 [8][512]
constexpr long o_yp    = o_ym    + 8L*512;          // [8][64][512]

typedef __attribute__((ext_vector_type(8))) short bf8_t;
typedef __attribute__((ext_vector_type(4))) float f4_t;

__device__ inline short f2bf(float f) {
    unsigned int u = __float_as_uint(f);
    unsigned int r = (u + 0x7FFFu + ((u >> 16) & 1u)) >> 16;
    return (short)r;
}

// ---------------- weight prep: fp32 transposes + Aneg + bf16 [N][K] transposes ----------------
__global__ void k_prep(const float* __restrict__ w1, const float* __restrict__ w2,
                       const float* __restrict__ win, const float* __restrict__ xw,
                       const float* __restrict__ alog, float* __restrict__ ws) {
    int idx = blockIdx.x * 256 + threadIdx.x;
    if (idx < 24576) {                        // wtx[k][n] = xw[n][k]  (fp32)
        int n_ = idx % 48; int k = idx / 48;
        ws[o_wtx + idx] = xw[n_*512 + k];
    } else if (idx < 32768) {                 // Aneg[j] = -exp(alog[j])  ([512][16])
        int j = idx - 24576;
        ws[o_aneg + j] = -__expf(alog[j]);
    } else if (idx < 557056) {                // bf16 region
        int j = idx - 32768;
        short* wsS = (short*)(ws + o_bf);
        if (j < 163840) {                     // wt1t[n][s*256+c] = w1[n][c][s]
            int n_ = j / 1280; int r = j - n_*1280; int s = r >> 8; int c = r & 255;
            wsS[j] = f2bf(w1[(n_*256 + c)*5 + s]);
        } else if (j < 262144) {              // wt2t[n][s*128+c] = w2[n][c][s]
            int jj = j - 163840;
            int n_ = jj / 384; int r = jj - n_*384; int s = r >> 7; int c = r & 127;
            wsS[j] = f2bf(w2[(n_*128 + c)*3 + s]);
        } else {                              // wtint[n][k] = win[n][k]
            int jj = j - 262144;
            int n_ = jj >> 8; int k = jj & 255;
            wsS[j] = f2bf(win[n_*256 + k]);
        }
    }
}

// ---------------- embedding gather -> padded bf16 [8][4100][256] ----------------
__global__ void k_embed(const int* __restrict__ tok, const float* __restrict__ emb,
                        short* __restrict__ xeb) {
    int idx = blockIdx.x * 256 + threadIdx.x;
    int r = idx >> 5;
    int c8 = (idx & 31) << 3;
    int b = r / 4100; int tr = r - b*4100;
    bf8_t v = {0,0,0,0,0,0,0,0};
    if (tr >= 2 && tr < 4098) {
        int t = tok[b*4096 + tr - 2];
        const float* e = emb + (long)t*256 + c8;
        #pragma unroll
        for (int i = 0; i < 8; ++i) v[i] = f2bf(e[i]);
    }
    *(bf8_t*)&xeb[(long)r*256 + c8] = v;
}

// ---------------- zero pad rows of out1b ----------------
__global__ void k_zpad(short* __restrict__ out1b) {
    int i = threadIdx.x;
    for (int j = i; j < 2048; j += 256) {
        int b = j >> 8; int rsel = (j >> 7) & 1; int c = j & 127;
        long row = (long)b*2050 + (rsel ? 2049 : 0);
        out1b[row*128 + c] = 0;
    }
}

// ---------------- LDS-staged double-buffered MFMA GEMM ----------------
template<int SHIFTS, int TPS, int EPI>
__global__ __launch_bounds__(256) void k_mgemm(const short* __restrict__ A, int ars, long batchA,
                                               const short* __restrict__ Bt, int ktot,
                                               const float* __restrict__ bias,
                                               short* __restrict__ outB, float* __restrict__ outF,
                                               int ors, long batchOut) {
    constexpr int KT = SHIFTS * TPS;
    constexpr int C  = TPS * 64;
    __shared__ short As[2][64][68];
    __shared__ short Bs[2][128][68];
    int tid = threadIdx.x;
    int l = tid & 63, w = tid >> 6;
    int m0 = blockIdx.x * 64;
    int n0 = blockIdx.y * 128;
    long zA = (long)blockIdx.z * batchA;
    long zO = (long)blockIdx.z * batchOut;

    bf8_t aReg[2], bReg[4];

    auto gload = [&](int kt) {
        int s = kt / TPS, c0 = (kt % TPS) * 64;
        const short* Ab = A + zA + (long)(m0 + s) * ars + c0;
        #pragma unroll
        for (int j = 0; j < 2; ++j) {
            int idx = tid + j*256;
            int r = idx >> 3, cc = (idx & 7) * 8;
            aReg[j] = *(const bf8_t*)&Ab[(long)r * ars + cc];
        }
        const short* Bb = Bt + (long)n0 * ktot + s * C + c0;
        #pragma unroll
        for (int j = 0; j < 4; ++j) {
            int idx = tid + j*256;
            int r = idx >> 3, cc = (idx & 7) * 8;
            bReg[j] = *(const bf8_t*)&Bb[(long)r * ktot + cc];
        }
    };
    auto lwrite = [&](int buf) {
        #pragma unroll
        for (int j = 0; j < 2; ++j) {
            int idx = tid + j*256;
            int r = idx >> 3, cc = (idx & 7) * 8;
            *(bf8_t*)&As[buf][r][cc] = aReg[j];
        }
        #pragma unroll
        for (int j = 0; j < 4; ++j) {
            int idx = tid + j*256;
            int r = idx >> 3, cc = (idx & 7) * 8;
            *(bf8_t*)&Bs[buf][r][cc] = bReg[j];
        }
    };

    f4_t acc[4][2];
    #pragma unroll
    for (int m = 0; m < 4; ++m)
        #pragma unroll
        for (int n = 0; n < 2; ++n) acc[m][n] = (f4_t){0.f, 0.f, 0.f, 0.f};

    gload(0);
    lwrite(0);
    __syncthreads();
    for (int kt = 0; kt < KT; ++kt) {
        int buf = kt & 1;
        if (kt + 1 < KT) gload(kt + 1);
        #pragma unroll
        for (int ks = 0; ks < 2; ++ks) {
            int kk = ks*32 + ((l >> 4) << 3);
            bf8_t a[4], b[2];
            #pragma unroll
            for (int m = 0; m < 4; ++m)
                a[m] = *(const bf8_t*)&As[buf][m*16 + (l & 15)][kk];
            #pragma unroll
            for (int n = 0; n < 2; ++n)
                b[n] = *(const bf8_t*)&Bs[buf][w*32 + n*16 + (l & 15)][kk];
            #pragma unroll
            for (int m = 0; m < 4; ++m)
                #pragma unroll
                for (int n = 0; n < 2; ++n)
                    acc[m][n] = __builtin_amdgcn_mfma_f32_16x16x32_bf16(a[m], b[n], acc[m][n], 0, 0, 0);
        }
        if (kt + 1 < KT) {
            lwrite(buf ^ 1);
            __syncthreads();
        }
    }

    #pragma unroll
    for (int mt = 0; mt < 4; ++mt)
        #pragma unroll
        for (int nt = 0; nt < 2; ++nt) {
            f4_t c = acc[mt][nt];
            int col = n0 + w*32 + nt*16 + (l & 15);
            int r0 = m0 + mt*16 + ((l >> 4) << 2);
            if constexpr (EPI == 0) {
                #pragma unroll
                for (int j = 0; j < 4; ++j)
                    outF[zO + (long)(r0 + j) * ors + col] = c[j];
            } else if constexpr (EPI == 1) {
                float bv = bias[col];
                #pragma unroll
                for (int j = 0; j < 4; ++j)
                    outB[zO + (long)(r0 + j) * ors + col] = f2bf(fmaxf(c[j] + bv, 0.f));
            } else {
                float bv = bias[col];
                float p0 = fmaxf(fmaxf(c[0], c[1]) + bv, 0.f);
                float p1 = fmaxf(fmaxf(c[2], c[3]) + bv, 0.f);
                int tp = r0 >> 1;
                outB[zO + (long)(tp + 1) * ors + col] = f2bf(p0);
                outB[zO + (long)(tp + 2) * ors + col] = f2bf(p1);
            }
        }
}

// ---------------- fp32 GEMM (x_proj, precision-sensitive) ----------------
template<int ACT>
__global__ __launch_bounds__(256) void k_gemm(const float* __restrict__ A, int lda,
                                              const float* __restrict__ WT,
                                              const float* __restrict__ bias,
                                              float* __restrict__ out,
                                              int M, int N, int K) {
    __shared__ float As[16][68];
    __shared__ float Bs[16][64];
    int n0 = blockIdx.x * 64, m0 = blockIdx.y * 64;
    int tid = threadIdx.x;
    int ti = tid >> 4, tj = tid & 15;
    float acc[4][4] = {};
    for (int k0 = 0; k0 < K; k0 += 16) {
        {
            int mm = tid >> 2, kq = tid & 3;
            float4 v = *(const float4*)&A[(long)(m0 + mm)*lda + k0 + kq*4];
            As[kq*4+0][mm] = v.x; As[kq*4+1][mm] = v.y;
            As[kq*4+2][mm] = v.z; As[kq*4+3][mm] = v.w;
        }
        {
            int kk = tid >> 4, n4 = tid & 15;
            float4 v = {0.f,0.f,0.f,0.f};
            if (n0 + n4*4 < N)
                v = *(const float4*)&WT[(long)(k0 + kk)*N + n0 + n4*4];
            *(float4*)&Bs[kk][n4*4] = v;
        }
        __syncthreads();
        #pragma unroll
        for (int kk = 0; kk < 16; ++kk) {
            float4 av = *(float4*)&As[kk][ti*4];
            float4 bv = *(float4*)&Bs[kk][tj*4];
            acc[0][0] += av.x*bv.x; acc[0][1] += av.x*bv.y; acc[0][2] += av.x*bv.z; acc[0][3] += av.x*bv.w;
            acc[1][0] += av.y*bv.x; acc[1][1] += av.y*bv.y; acc[1][2] += av.y*bv.z; acc[1][3] += av.y*bv.w;
            acc[2][0] += av.z*bv.x; acc[2][1] += av.z*bv.y; acc[2][2] += av.z*bv.z; acc[2][3] += av.z*bv.w;
            acc[3][0] += av.w*bv.x; acc[3][1] += av.w*bv.y; acc[3][2] += av.w*bv.z; acc[3][3] += av.w*bv.w;
        }
        __syncthreads();
    }
    if (n0 + tj*4 >= N) return;
    float4 bv = {0.f,0.f,0.f,0.f};
    if (bias) bv = *(const float4*)&bias[n0 + tj*4];
    #pragma unroll
    for (int i = 0; i < 4; ++i) {
        int m = m0 + ti*4 + i;
        float4 v;
        v.x = acc[i][0] + bv.x; v.y = acc[i][1] + bv.y;
        v.z = acc[i][2] + bv.z; v.w = acc[i][3] + bv.w;
        if (ACT == 1) {
            v.x = (v.x > 20.f) ? v.x : log1pf(__expf(v.x));
            v.y = (v.y > 20.f) ? v.y : log1pf(__expf(v.y));
            v.z = (v.z > 20.f) ? v.z : log1pf(__expf(v.z));
            v.w = (v.w > 20.f) ? v.w : log1pf(__expf(v.w));
        }
        *(float4*)&out[(long)m*N + n0 + tj*4] = v;
    }
}

// ---------------- causal depthwise conv (k=4) + SiLU : LDS weights, 4t/thread ----------------
__global__ __launch_bounds__(256) void k_dwconv(const float* __restrict__ xz,
                                                const float* __restrict__ wdw,
                                                const float* __restrict__ bdw,
                                                float* __restrict__ xout) {
    __shared__ float wk[4][512];
    __shared__ float bs[512];
    int tid = threadIdx.x;
    for (int e = tid; e < 2048; e += 256) {
        int k = e >> 9, d = e & 511;
        wk[k][d] = wdw[d*4 + k];
    }
    bs[tid] = bdw[tid];
    bs[tid + 256] = bdw[tid + 256];
    __syncthreads();

    int idx = blockIdx.x * 256 + tid;        // (b, tg, d4): 8*512*128
    int d4 = idx & 127;
    int tg = (idx >> 7) & 511;
    int b  = idx >> 16;
    int d0 = d4 * 4;
    int t0 = tg * 4;

    float4 x[7];
    #pragma unroll
    for (int i = 0; i < 7; ++i) {
        int t = t0 - 3 + i;
        x[i] = (t >= 0) ? *(const float4*)&xz[((long)(b*Lh + t))*1024 + d0]
                        : (float4){0.f, 0.f, 0.f, 0.f};
    }
    float4 w[4];
    #pragma unroll
    for (int k = 0; k < 4; ++k) w[k] = *(float4*)&wk[k][d0];
    float4 bias4 = *(float4*)&bs[d0];

    #pragma unroll
    for (int j = 0; j < 4; ++j) {
        float4 a = bias4;
        #pragma unroll
        for (int k = 0; k < 4; ++k) {
            float4 v = x[j + k];
            a.x += v.x * w[k].x; a.y += v.y * w[k].y;
            a.z += v.z * w[k].z; a.w += v.w * w[k].w;
        }
        a.x = a.x / (1.f + __expf(-a.x));
        a.y = a.y / (1.f + __expf(-a.y));
        a.z = a.z / (1.f + __expf(-a.z));
        a.w = a.w / (1.f + __expf(-a.w));
        *(float4*)&xout[((long)(b*Lh + t0 + j))*512 + d0] = a;
    }
}

// ---------------- chunked selective scan ----------------
// Phase A (dt_proj fused): local scan (h=0); emits hend, P=q, S[n]=Σ gate·C_n·q_n,
// ypart=Σ gate·(C·h_local + x·Dp).  State layout [b][c][d][16] (coalesced).
__global__ __launch_bounds__(256) void k_scan_a(const float* __restrict__ x,
                                                const float* __restrict__ xz,
                                                const float* __restrict__ dbc,
                                                const float* __restrict__ dtw,
                                                const float* __restrict__ dtb,
                                                const float* __restrict__ Aneg,
                                                const float* __restrict__ Dp,
                                                float* __restrict__ hend,
                                                float* __restrict__ Pbuf,
                                                float* __restrict__ Sbuf,
                                                float* __restrict__ ypart) {
    __shared__ float4 Ds4[TC][4], Bs4[TC][4], Cs4[TC][4];
    int c = blockIdx.x;
    int b = blockIdx.z;
    int tid = threadIdx.x;
    int d = blockIdx.y * 256 + tid;
    for (int i = tid; i < TC*4; i += 256) {
        int tt = i >> 2, qq = i & 3;
        long rb = ((long)b*Lh + c*TC + tt)*48;
        Ds4[tt][qq] = *(const float4*)&dbc[rb + qq*4];
        Bs4[tt][qq] = *(const float4*)&dbc[rb + 16 + qq*4];
        Cs4[tt][qq] = *(const float4*)&dbc[rb + 32 + qq*4];
    }
    __syncthreads();
    float A_[16], wdt[16];
    #pragma unroll
    for (int qq = 0; qq < 4; ++qq)
        *(float4*)&A_[qq*4] = *(const float4*)&Aneg[d*16 + qq*4];
    #pragma unroll
    for (int qq = 0; qq < 4; ++qq)
        *(float4*)&wdt[qq*4] = *(const float4*)&dtw[d*16 + qq*4];
    float dtbd = dtb[d];
    float h[16], q[16], S[16];
    #pragma unroll
    for (int n = 0; n < 16; ++n) { h[n] = 0.f; q[n] = 1.f; S[n] = 0.f; }
    float Dpv = Dp[d];
    float yp = 0.f;
    long base  = ((long)b*Lh + c*TC)*512 + d;
    long zbase = ((long)b*Lh + c*TC)*1024 + 512 + d;
    for (int tt = 0; tt < TC; ++tt) {
        float dr[16];
        *(float4*)&dr[0]  = Ds4[tt][0]; *(float4*)&dr[4]  = Ds4[tt][1];
        *(float4*)&dr[8]  = Ds4[tt][2]; *(float4*)&dr[12] = Ds4[tt][3];
        float raw = dtbd;
        #pragma unroll
        for (int k = 0; k < 16; ++k) raw += dr[k] * wdt[k];
        float dtv = (raw > 20.f) ? raw : log1pf(__expf(raw));
        float xv  = x[base + (long)tt*512];
        float zv  = xz[zbase + (long)tt*1024];
        float u = dtv * xv;
        float gate = zv / (1.f + __expf(-zv));
        float Bv[16], Cv[16];
        *(float4*)&Bv[0]  = Bs4[tt][0]; *(float4*)&Bv[4]  = Bs4[tt][1];
        *(float4*)&Bv[8]  = Bs4[tt][2]; *(float4*)&Bv[12] = Bs4[tt][3];
        *(float4*)&Cv[0]  = Cs4[tt][0]; *(float4*)&Cv[4]  = Cs4[tt][1];
        *(float4*)&Cv[8]  = Cs4[tt][2]; *(float4*)&Cv[12] = Cs4[tt][3];
        float p = 0.f;
        #pragma unroll
        for (int n = 0; n < 16; ++n) {
            float dA = __expf(dtv * A_[n]);
            h[n] = h[n] * dA + u * Bv[n];
            q[n] *= dA;
            p += h[n] * Cv[n];
            S[n] += (gate * Cv[n]) * q[n];
        }
        yp += gate * (p + xv * Dpv);
    }
    long o = (((long)b*NCH + c)*512 + d)*16;
    #pragma unroll
    for (int n = 0; n < 16; ++n) hend[o + n] = h[n];
    #pragma unroll
    for (int n = 0; n < 16; ++n) Pbuf[o + n] = q[n];
    #pragma unroll
    for (int n = 0; n < 16; ++n) Sbuf[o + n] = S[n];
    ypart[((long)b*NCH + c)*512 + d] = yp;
}

// Phase BC fused: lane (b,d,n) serially combines chunks, accumulating S·h_in inline;
// then adds ypart and 16-lane shuffle-reduces -> ym[b][d].  Coalesced reads.
__global__ __launch_bounds__(256) void k_scan_bc(const float* __restrict__ hend,
                                                 const float* __restrict__ Pbuf,
                                                 const float* __restrict__ Sbuf,
                                                 const float* __restrict__ ypart,
                                                 float* __restrict__ ym) {
    int idx = blockIdx.x * 256 + threadIdx.x;   // (b,d,n): 65536
    int n = idx & 15;
    long bd = idx >> 4;
    int d = (int)(bd & 511);
    int b = (int)(bd >> 9);
    float h = 0.f, acc = 0.f;
    for (int c = 0; c < NCH; ++c) {
        long o = (((long)b*NCH + c)*512 + d)*16 + n;
        acc += Sbuf[o] * h;                  // h = carry-in for chunk c
        h = hend[o] + Pbuf[o] * h;
    }
    #pragma unroll
    for (int k = 0; k < NCH/16; ++k)
        acc += ypart[((long)b*NCH + (n + k*16))*512 + d];
    acc += __shfl_xor(acc, 1);
    acc += __shfl_xor(acc, 2);
    acc += __shfl_xor(acc, 4);
    acc += __shfl_xor(acc, 8);
    if (n == 0) ym[bd] = acc;
}

// ---------------- tail: xm = (ym/2048) @ ow^T ; logits = xm @ fcw^T + fcb ----------------
__global__ void k_tail(const float* __restrict__ ym, const float* __restrict__ ow,
                       const float* __restrict__ fcw, const float* __restrict__ fcb,
                       float* __restrict__ out) {
    __shared__ float yls[512];
    __shared__ float xs[256];
    int b = blockIdx.x, c = threadIdx.x;
    yls[c] = ym[b*512 + c];
    yls[c + 256] = ym[b*512 + 256 + c];
    __syncthreads();
    float s = 0.f;
    for (int d = 0; d < 512; ++d) s += yls[d] * ow[c*512 + d];
    xs[c] = s * (1.f / 2048.f);
    __syncthreads();
    if (c < 10) {
        float t = fcb[c];
        for (int k = 0; k < 256; ++k) t += xs[k] * fcw[c*256 + k];
        out[b*10 + c] = t;
    }
}

extern "C" void kernel_launch(void* const* d_in, const int* in_sizes, int n_in,
                              void* d_out, int out_size, void* d_ws, size_t ws_size,
                              hipStream_t stream) {
    const int*   tok  = (const int*)d_in[0];
    const float* emb  = (const float*)d_in[1];
    const float* w1   = (const float*)d_in[2];
    const float* b1   = (const float*)d_in[3];
    const float* w2   = (const float*)d_in[4];
    const float* b2   = (const float*)d_in[5];
    const float* win  = (const float*)d_in[6];
    const float* wdw  = (const float*)d_in[7];
    const float* bdw  = (const float*)d_in[8];
    const float* xw   = (const float*)d_in[9];
    const float* dtw  = (const float*)d_in[10];
    const float* dtb  = (const float*)d_in[11];
    const float* alog = (const float*)d_in[12];
    const float* Dp   = (const float*)d_in[13];
    const float* ow   = (const float*)d_in[14];
    const float* fcw  = (const float*)d_in[15];
    const float* fcb  = (const float*)d_in[16];
    float* ws  = (float*)d_ws;
    float* out = (float*)d_out;

    float* wtx   = ws + o_wtx;
    float* aneg  = ws + o_aneg;
    short* wt1t  = (short*)(ws + o_bf);
    short* wt2t  = wt1t + 163840;
    short* wtint = wt2t + 98304;
    short* xeb   = (short*)(ws + o_xeb);
    short* out1b = (short*)(ws + o_out1b);
    short* ub    = (short*)(ws + o_ub);
    float* xz    = ws + o_xz;
    float* xbuf  = ws + o_xbuf;
    float* dbc   = ws + o_dbc;
    float* hend  = ws + o_hend;
    float* Pbuf  = ws + o_P;
    float* Sbuf  = ws + o_S;
    float* ym    = ws + o_ym;
    float* ypart = ws + o_yp;

    // 1. weight prep (+ Aneg precompute)
    k_prep<<<2176, 256, 0, stream>>>(w1, w2, win, xw, alog, ws);
    // 2. embedding -> padded bf16 xe [8][4100][256]
    k_embed<<<4100, 256, 0, stream>>>(tok, emb, xeb);
    // 3. zero pad rows of out1b
    k_zpad<<<1, 256, 0, stream>>>(out1b);
    // 4. conv1 (K=1280, C=256) + relu + pool -> out1b bf16 [8][2050][128]
    k_mgemm<5, 4, 2><<<dim3(64, 1, 8), 256, 0, stream>>>(
        xeb, 256, 4100L*256, wt1t, 1280, b1, out1b, nullptr, 128, 2050L*128);
    // 5. conv2 (K=384, C=128) + relu -> ub bf16 [16384][256]
    k_mgemm<3, 2, 1><<<dim3(32, 2, 8), 256, 0, stream>>>(
        out1b, 128, 2050L*128, wt2t, 384, b2, ub, nullptr, 256, 2048L*256);
    // 6. in_proj (K=256) -> xz fp32 [16384][1024]
    k_mgemm<1, 4, 0><<<dim3(256, 8, 1), 256, 0, stream>>>(
        ub, 256, 0, wtint, 256, nullptr, nullptr, xz, 1024, 0);
    // 7. depthwise conv + silu -> xbuf fp32 [16384][512]
    k_dwconv<<<2048, 256, 0, stream>>>(xz, wdw, bdw, xbuf);
    // 8. x_proj (fp32) -> dbc [16384][48]
    k_gemm<0><<<dim3(1, M2/64), 256, 0, stream>>>(xbuf, Din, wtx, nullptr, dbc, M2, 48, Din);
    // 9. chunked selective scan (dt_proj fused): A emits (hend,P,S,ypart); BC combines+reduces
    k_scan_a<<<dim3(NCH, 2, Bn), 256, 0, stream>>>(xbuf, xz, dbc, dtw, dtb, aneg, Dp,
                                                   hend, Pbuf, Sbuf, ypart);
    k_scan_bc<<<(Bn*Din*Nst)/256, 256, 0, stream>>>(hend, Pbuf, Sbuf, ypart, ym);
    // 10. tail: out_proj on means + fc -> logits
    k_tail<<<8, 256, 0, stream>>>(ym, ow, fcw, fcb, out);
}